// Round 2
// baseline (1164.021 us; speedup 1.0000x reference)
//
#include <hip/hip_runtime.h>

// images [64,256,256,3] f32 NHWC; output flow [64,2,64,64] f32
// conv1: 3->32 k5 s2 p2 relu -> [64,32,128,128]
// conv2: 32->32 k5 s2 p2 relu -> [64,32,64,64]   (z-split 2x16 channels)
// MLP:   4->256 relu ->800 -> per-sample kernels [64,32,5,5]
// xconv: depthwise per-sample k5 p2 (LDS plane staging)
// mp1:   32->32 k3 p1 relu                        (z-split 2x16 channels)
// mp2:   32->2  k3 p1 (2 px/thread)

__device__ __forceinline__ int iclamp(int v, int lo, int hi) {
    return v < lo ? lo : (v > hi ? hi : v);
}

// Repack weights src[o][i][t] (O,I,T) -> dst[(i*T+t)*O + o]
__global__ __launch_bounds__(256) void repack_kernel(const float* __restrict__ src,
                                                     float* __restrict__ dst,
                                                     int O, int I, int T) {
    int idx = blockIdx.x * 256 + threadIdx.x;
    int total = O * I * T;
    if (idx >= total) return;
    int it = I * T;
    int o = idx / it;
    int r = idx - o * it;
    dst[r * O + o] = src[idx];
}

// Action MLP: actions[64,4] -> hidden[256] relu -> out[800]
// grid (4, 64) block 256; block x covers 200 outputs
__global__ __launch_bounds__(256) void mlp_kernel(const float* __restrict__ actions,
                                                  const float* __restrict__ w1,
                                                  const float* __restrict__ b1,
                                                  const float* __restrict__ w2,
                                                  const float* __restrict__ b2,
                                                  float* __restrict__ aout) {
    int n = blockIdx.y;
    int t = threadIdx.x; // 0..255
    __shared__ float hid[256];
    float a0 = actions[n * 4 + 0], a1 = actions[n * 4 + 1];
    float a2 = actions[n * 4 + 2], a3 = actions[n * 4 + 3];
    float acc = b1[t];
    acc += a0 * w1[0 * 256 + t] + a1 * w1[1 * 256 + t] +
           a2 * w1[2 * 256 + t] + a3 * w1[3 * 256 + t];
    hid[t] = fmaxf(acc, 0.0f);
    __syncthreads();
    int o = blockIdx.x * 200 + t;
    if (t < 200) {
        float s = b2[o];
        #pragma unroll 4
        for (int i = 0; i < 256; ++i) s += hid[i] * w2[i * 800 + o];
        aout[n * 800 + o] = s;
    }
}

// conv1: img NHWC [64,256,256,3] -> h1 [64,32,128,128], k5 s2 p2, relu
// wT layout [(c*25+tap)*32 + o]
__global__ __launch_bounds__(256) void conv1_kernel(const float* __restrict__ img,
                                                    const float* __restrict__ wT,
                                                    const float* __restrict__ bias,
                                                    float* __restrict__ out) {
    const int ox = threadIdx.x;                    // 0..127
    const int oy = blockIdx.x * 2 + threadIdx.y;   // 0..127
    const int n = blockIdx.y;
    float acc[32];
    #pragma unroll
    for (int o = 0; o < 32; ++o) acc[o] = bias[o];

    #pragma unroll
    for (int kh = 0; kh < 5; ++kh) {
        const int iy = 2 * oy - 2 + kh;
        if (iy < 0 || iy >= 256) continue;   // wave-uniform
        const float* rowp = img + ((size_t)n * 256 + iy) * 256 * 3;
        #pragma unroll
        for (int kw = 0; kw < 5; ++kw) {
            const int ix = 2 * ox - 2 + kw;
            const int ixc = iclamp(ix, 0, 255);
            const float* p = rowp + (size_t)ixc * 3;
            float v0 = p[0], v1 = p[1], v2 = p[2];
            if (ix != ixc) { v0 = 0.0f; v1 = 0.0f; v2 = 0.0f; }
            const int tap = kh * 5 + kw;
            const float* w0 = wT + (0 * 25 + tap) * 32;
            const float* w1 = wT + (1 * 25 + tap) * 32;
            const float* w2 = wT + (2 * 25 + tap) * 32;
            #pragma unroll
            for (int o = 0; o < 32; ++o)
                acc[o] += w0[o] * v0 + w1[o] * v1 + w2[o] * v2;
        }
    }
    size_t base = (size_t)n * 32 * 16384 + (size_t)oy * 128 + ox;
    #pragma unroll
    for (int o = 0; o < 32; ++o)
        out[base + (size_t)o * 16384] = fmaxf(acc[o], 0.0f);
}

// conv2: h1 [64,32,128,128] -> h2 [64,32,64,64], k5 s2 p2, relu
// wT layout [(ci*25+tap)*32 + o]; blockIdx.z selects 16-channel half
__global__ __launch_bounds__(256, 8) void conv2_kernel(const float* __restrict__ in,
                                                       const float* __restrict__ wT,
                                                       const float* __restrict__ bias,
                                                       float* __restrict__ out) {
    const int ox = threadIdx.x;                    // 0..63
    const int oy = blockIdx.x * 4 + threadIdx.y;   // 0..63
    const int n  = blockIdx.y;
    const int ob = blockIdx.z * 16;
    float acc[16];
    #pragma unroll
    for (int o = 0; o < 16; ++o) acc[o] = bias[ob + o];

    const float* inn = in + (size_t)n * 32 * 16384;
    const int iy0 = 2 * oy - 2;
    const int ix0 = 2 * ox - 2;
    for (int ci = 0; ci < 32; ++ci) {
        const float* ip = inn + (size_t)ci * 16384;
        const float* wci = wT + ci * 800 + ob;   // 25*32
        #pragma unroll
        for (int kh = 0; kh < 5; ++kh) {
            const int iy = iy0 + kh;
            const bool rowok = (iy >= 0) & (iy < 128);
            const float* row = ip + (size_t)(rowok ? iy : 0) * 128;
            float v[5];
            #pragma unroll
            for (int kw = 0; kw < 5; ++kw) {
                const int ix = ix0 + kw;
                const int ixc = iclamp(ix, 0, 127);
                float t = row[ixc];
                v[kw] = (rowok && ix == ixc) ? t : 0.0f;
            }
            const float* wk = wci + kh * 160;    // 5*32
            #pragma unroll
            for (int kw = 0; kw < 5; ++kw) {
                #pragma unroll
                for (int o = 0; o < 16; ++o) acc[o] += wk[kw * 32 + o] * v[kw];
            }
        }
    }
    size_t base = (size_t)n * 32 * 4096 + (size_t)ob * 4096 + (size_t)oy * 64 + ox;
    #pragma unroll
    for (int o = 0; o < 16; ++o)
        out[base + (size_t)o * 4096] = fmaxf(acc[o], 0.0f);
}

// cross-conv: one workgroup per (n,c) plane; LDS-staged 68x68 padded tile
__global__ __launch_bounds__(256, 8) void xconv_kernel(const float* __restrict__ in,
                                                       const float* __restrict__ ker,
                                                       float* __restrict__ out) {
    __shared__ float tile[68 * 68];
    const int tid = threadIdx.x;
    const int nc = blockIdx.x;                     // 0..2047
    for (int i = tid; i < 68 * 68; i += 256) tile[i] = 0.0f;
    __syncthreads();
    const float* ip = in + (size_t)nc * 4096;
    for (int i = tid; i < 4096; i += 256) {
        int r = i >> 6, c = i & 63;
        tile[(r + 2) * 68 + (c + 2)] = ip[i];
    }
    const float* kp = ker + (size_t)nc * 25;
    float k[25];
    #pragma unroll
    for (int t = 0; t < 25; ++t) k[t] = kp[t];
    __syncthreads();

    const int ox = tid & 63;
    const int ys = (tid >> 6) * 4;                 // 0,4,8,12
    float* op = out + (size_t)nc * 4096;
    #pragma unroll
    for (int g = 0; g < 4; ++g) {
        const int oy0 = ys + g * 16;               // strip start row
        float a[4] = {0.0f, 0.0f, 0.0f, 0.0f};
        #pragma unroll
        for (int kw = 0; kw < 5; ++kw) {
            #pragma unroll
            for (int r = 0; r < 8; ++r) {
                float v = tile[(oy0 + r) * 68 + ox + kw];
                #pragma unroll
                for (int j = 0; j < 4; ++j) {
                    const int kh = r - j;
                    if (kh >= 0 && kh <= 4) a[j] += k[kh * 5 + kw] * v;
                }
            }
        }
        #pragma unroll
        for (int j = 0; j < 4; ++j)
            op[(size_t)(oy0 + j) * 64 + ox] = a[j];
    }
}

// mp1: sa [64,32,64,64] -> f [64,32,64,64], k3 p1, relu
// wT layout [(ci*9+tap)*32 + o]; blockIdx.z selects 16-channel half
__global__ __launch_bounds__(256, 8) void mp1_kernel(const float* __restrict__ in,
                                                     const float* __restrict__ wT,
                                                     const float* __restrict__ bias,
                                                     float* __restrict__ out) {
    const int ox = threadIdx.x;                    // 0..63
    const int oy = blockIdx.x * 4 + threadIdx.y;   // 0..63
    const int n  = blockIdx.y;
    const int ob = blockIdx.z * 16;
    float acc[16];
    #pragma unroll
    for (int o = 0; o < 16; ++o) acc[o] = bias[ob + o];

    const float* inn = in + (size_t)n * 32 * 4096;
    for (int ci = 0; ci < 32; ++ci) {
        const float* ip = inn + (size_t)ci * 4096;
        const float* wci = wT + ci * 288 + ob;     // 9*32
        float v[9];
        #pragma unroll
        for (int kh = 0; kh < 3; ++kh) {
            const int iy = oy - 1 + kh;
            const bool rowok = (iy >= 0) & (iy < 64);
            const float* row = ip + (size_t)(rowok ? iy : 0) * 64;
            #pragma unroll
            for (int kw = 0; kw < 3; ++kw) {
                const int ix = ox - 1 + kw;
                const int ixc = iclamp(ix, 0, 63);
                float t = row[ixc];
                v[kh * 3 + kw] = (rowok && ix == ixc) ? t : 0.0f;
            }
        }
        #pragma unroll
        for (int tap = 0; tap < 9; ++tap) {
            #pragma unroll
            for (int o = 0; o < 16; ++o) acc[o] += wci[tap * 32 + o] * v[tap];
        }
    }
    size_t base = (size_t)n * 32 * 4096 + (size_t)ob * 4096 + (size_t)oy * 64 + ox;
    #pragma unroll
    for (int o = 0; o < 16; ++o)
        out[base + (size_t)o * 4096] = fmaxf(acc[o], 0.0f);
}

// mp2: f [64,32,64,64] -> flow [64,2,64,64], k3 p1; 2 x-pixels per thread
// wT layout [(ci*9+tap)*2 + o]
__global__ __launch_bounds__(256) void mp2_kernel(const float* __restrict__ in,
                                                  const float* __restrict__ wT,
                                                  const float* __restrict__ bias,
                                                  float* __restrict__ out) {
    const int ox0 = threadIdx.x * 2;               // 0..62
    const int oy  = blockIdx.x * 8 + threadIdx.y;  // 0..63
    const int n   = blockIdx.y;
    float a00 = bias[0], a01 = bias[0];
    float a10 = bias[1], a11 = bias[1];

    const float* inn = in + (size_t)n * 131072;
    for (int ci = 0; ci < 32; ++ci) {
        const float* ip = inn + (size_t)ci * 4096;
        const float* w = wT + ci * 18;
        #pragma unroll
        for (int kh = 0; kh < 3; ++kh) {
            const int iy = oy - 1 + kh;
            const bool rowok = (iy >= 0) & (iy < 64);
            const float* row = ip + (size_t)(rowok ? iy : 0) * 64;
            float v[4];
            #pragma unroll
            for (int c = 0; c < 4; ++c) {
                const int ix = ox0 - 1 + c;
                const int ixc = iclamp(ix, 0, 63);
                float t = row[ixc];
                v[c] = (rowok && ix == ixc) ? t : 0.0f;
            }
            #pragma unroll
            for (int kw = 0; kw < 3; ++kw) {
                const float w0 = w[(kh * 3 + kw) * 2];
                const float w1 = w[(kh * 3 + kw) * 2 + 1];
                a00 += w0 * v[kw]; a01 += w0 * v[kw + 1];
                a10 += w1 * v[kw]; a11 += w1 * v[kw + 1];
            }
        }
    }
    size_t base = (size_t)n * 8192 + (size_t)oy * 64 + ox0;
    out[base]        = a00; out[base + 1]        = a01;
    out[base + 4096] = a10; out[base + 4096 + 1] = a11;
}

extern "C" void kernel_launch(void* const* d_in, const int* in_sizes, int n_in,
                              void* d_out, int out_size, void* d_ws, size_t ws_size,
                              hipStream_t stream) {
    (void)in_sizes; (void)n_in; (void)out_size; (void)ws_size;
    const float* images  = (const float*)d_in[0];
    const float* actions = (const float*)d_in[1];
    const float* pe_w1   = (const float*)d_in[2];
    const float* pe_b1   = (const float*)d_in[3];
    const float* pe_w2   = (const float*)d_in[4];
    const float* pe_b2   = (const float*)d_in[5];
    const float* ae_w1   = (const float*)d_in[6];
    const float* ae_b1   = (const float*)d_in[7];
    const float* ae_w2   = (const float*)d_in[8];
    const float* ae_b2   = (const float*)d_in[9];
    const float* mp_w1   = (const float*)d_in[10];
    const float* mp_b1   = (const float*)d_in[11];
    const float* mp_w2   = (const float*)d_in[12];
    const float* mp_b2   = (const float*)d_in[13];
    float* out = (float*)d_out;

    char* ws = (char*)d_ws;
    float* a_ker = (float*)(ws + 0);            // 64*800*4      = 204800
    float* w1T   = (float*)(ws + 204800);       // 2400*4        = 9600
    float* w2T   = (float*)(ws + 214400);       // 25600*4       = 102400
    float* mp1T  = (float*)(ws + 316800);       // 9216*4        = 36864
    float* mp2T  = (float*)(ws + 353664);       // 576*4         = 2304
    float* h1    = (float*)(ws + 524288);       // 64*32*128*128*4 = 134217728
    float* h2    = (float*)(ws + 524288 + 134217728); // 64*32*64*64*4 = 33554432
    float* sa    = h1;                          // reuse h1 region (dead after conv2)
    float* f     = (float*)((char*)h1 + 33554432);

    repack_kernel<<<10, 256, 0, stream>>>(pe_w1, w1T, 32, 3, 25);
    repack_kernel<<<100, 256, 0, stream>>>(pe_w2, w2T, 32, 32, 25);
    repack_kernel<<<36, 256, 0, stream>>>(mp_w1, mp1T, 32, 32, 9);
    repack_kernel<<<3, 256, 0, stream>>>(mp_w2, mp2T, 2, 32, 9);

    mlp_kernel<<<dim3(4, 64), 256, 0, stream>>>(actions, ae_w1, ae_b1, ae_w2, ae_b2, a_ker);
    conv1_kernel<<<dim3(64, 64), dim3(128, 2), 0, stream>>>(images, w1T, pe_b1, h1);
    conv2_kernel<<<dim3(16, 64, 2), dim3(64, 4), 0, stream>>>(h1, w2T, pe_b2, h2);
    xconv_kernel<<<2048, 256, 0, stream>>>(h2, a_ker, sa);
    mp1_kernel<<<dim3(16, 64, 2), dim3(64, 4), 0, stream>>>(sa, mp1T, mp_b1, f);
    mp2_kernel<<<dim3(8, 64), dim3(32, 8), 0, stream>>>(f, mp2T, mp_b2, out);
}

// Round 3
// 376.839 us; speedup vs baseline: 3.0889x; 3.0889x over previous
//
#include <hip/hip_runtime.h>

// Pipeline (all activations NHWC bf16 with zero-padded borders, rebuilt every launch):
//  images [64,256,256,3] f32 NHWC
//  conv1 (fp32 VALU): 3->32 k5 s2 p2 relu -> h1p [64,132,132,32] bf16 (pad 2)
//  conv2 (MFMA 16x16x32 bf16): 32->32 k5 s2 p2 relu -> h2p [64,68,68,32] bf16 (pad 2)
//  MLP -> per-sample kernels [64,32,25] f32
//  xconv (LDS, fp32 math): depthwise k5 p2 -> sap [64,66,66,32] bf16 (pad 1)
//  mp1 (MFMA): 32->32 k3 p1 relu -> fp [64,66,66,32] bf16 (pad 1)
//  mp2 (fp32): 32->2 k3 p1 -> flow [64,2,64,64] f32 (d_out)

typedef __attribute__((ext_vector_type(8))) short bf16x8;
typedef __attribute__((ext_vector_type(4))) float f32x4;

__device__ __forceinline__ unsigned short f2bf(float f) {
    unsigned int u = __float_as_uint(f);
    u = (u + 0x7FFFu + ((u >> 16) & 1u)) >> 16;   // RNE
    return (unsigned short)u;
}
__device__ __forceinline__ float bf2f(unsigned short h) {
    return __uint_as_float(((unsigned int)h) << 16);
}

// Zero the pad border of a [64][R][R][32] bf16 tensor (viewed as uint, 16 uints/cell).
__global__ __launch_bounds__(64) void zero_border_kernel(unsigned int* t, int R, int pad) {
    int row = blockIdx.x % R;
    int n   = blockIdx.x / R;
    int tid = threadIdx.x;
    unsigned int* rp = t + (size_t)(n * R + row) * R * 16;
    if (row < pad || row >= R - pad) {
        for (int i = tid; i < R * 16; i += 64) rp[i] = 0u;
    } else {
        for (int i = tid; i < pad * 16; i += 64) {
            rp[i] = 0u;
            rp[(size_t)(R - pad) * 16 + i] = 0u;
        }
    }
}

// pe_w1 [32][3][25] f32 -> w1T [(c*25+tap)*32+o] f32
__global__ __launch_bounds__(256) void repack_conv1(const float* __restrict__ src, float* __restrict__ dst) {
    int idx = blockIdx.x * 256 + threadIdx.x;
    if (idx >= 2400) return;
    int o = idx / 75, r = idx % 75;
    dst[r * 32 + o] = src[idx];
}
// pe_w2 [32][32][25] f32 -> B2 bf16 [(tap*32+co)*32+ci]
__global__ __launch_bounds__(256) void repack_conv2(const float* __restrict__ src, unsigned short* __restrict__ dst) {
    int idx = blockIdx.x * 256 + threadIdx.x;
    if (idx >= 25600) return;
    int co = idx / 800, r = idx % 800, ci = r / 25, tap = r % 25;
    dst[(tap * 32 + co) * 32 + ci] = f2bf(src[idx]);
}
// mp_w1 [32][32][9] f32 -> Bm1 bf16 [(tap*32+co)*32+ci]
__global__ __launch_bounds__(256) void repack_mp1(const float* __restrict__ src, unsigned short* __restrict__ dst) {
    int idx = blockIdx.x * 256 + threadIdx.x;
    if (idx >= 9216) return;
    int co = idx / 288, r = idx % 288, ci = r / 9, tap = r % 9;
    dst[(tap * 32 + co) * 32 + ci] = f2bf(src[idx]);
}
// mp_w2 [2][32][9] f32 -> w2p f32 [(tap*32+ci)*2+o]
__global__ __launch_bounds__(256) void repack_mp2(const float* __restrict__ src, float* __restrict__ dst) {
    int idx = blockIdx.x * 256 + threadIdx.x;
    if (idx >= 576) return;
    int o = idx / 288, r = idx % 288, ci = r / 9, tap = r % 9;
    dst[(tap * 32 + ci) * 2 + o] = src[idx];
}

// Action MLP: actions[64,4] -> relu(256) -> 800; grid (4,64)
__global__ __launch_bounds__(256) void mlp_kernel(const float* __restrict__ actions,
                                                  const float* __restrict__ w1,
                                                  const float* __restrict__ b1,
                                                  const float* __restrict__ w2,
                                                  const float* __restrict__ b2,
                                                  float* __restrict__ aout) {
    int n = blockIdx.y;
    int t = threadIdx.x;
    __shared__ float hid[256];
    float a0 = actions[n * 4 + 0], a1 = actions[n * 4 + 1];
    float a2 = actions[n * 4 + 2], a3 = actions[n * 4 + 3];
    float acc = b1[t];
    acc += a0 * w1[0 * 256 + t] + a1 * w1[1 * 256 + t] +
           a2 * w1[2 * 256 + t] + a3 * w1[3 * 256 + t];
    hid[t] = fmaxf(acc, 0.0f);
    __syncthreads();
    int o = blockIdx.x * 200 + t;
    if (t < 200) {
        float s = b2[o];
        #pragma unroll 4
        for (int i = 0; i < 256; ++i) s += hid[i] * w2[i * 800 + o];
        aout[n * 800 + o] = s;
    }
}

// conv1: img NHWC f32 -> h1p [64][132][132][32] bf16 (interior 2..129)
__global__ __launch_bounds__(256) void conv1_kernel(const float* __restrict__ img,
                                                    const float* __restrict__ wT,
                                                    const float* __restrict__ bias,
                                                    unsigned short* __restrict__ h1p) {
    const int ox = threadIdx.x;                    // 0..127
    const int oy = blockIdx.x * 2 + threadIdx.y;   // 0..127
    const int n = blockIdx.y;
    float acc[32];
    #pragma unroll
    for (int o = 0; o < 32; ++o) acc[o] = bias[o];

    #pragma unroll
    for (int kh = 0; kh < 5; ++kh) {
        const int iy = 2 * oy - 2 + kh;
        if (iy < 0 || iy >= 256) continue;   // wave-uniform
        const float* rowp = img + ((size_t)n * 256 + iy) * 768;
        #pragma unroll
        for (int kw = 0; kw < 5; ++kw) {
            const int ix = 2 * ox - 2 + kw;
            const int ixc = ix < 0 ? 0 : (ix > 255 ? 255 : ix);
            const float* p = rowp + ixc * 3;
            float v0 = p[0], v1 = p[1], v2 = p[2];
            if (ix != ixc) { v0 = 0.f; v1 = 0.f; v2 = 0.f; }
            const int tap = kh * 5 + kw;
            const float* w0 = wT + (0 * 25 + tap) * 32;
            const float* w1 = wT + (1 * 25 + tap) * 32;
            const float* w2 = wT + (2 * 25 + tap) * 32;
            #pragma unroll
            for (int o = 0; o < 32; ++o)
                acc[o] += w0[o] * v0 + w1[o] * v1 + w2[o] * v2;
        }
    }
    unsigned int u[16];
    #pragma unroll
    for (int i = 0; i < 16; ++i) {
        float lo = fmaxf(acc[2 * i], 0.f), hi = fmaxf(acc[2 * i + 1], 0.f);
        u[i] = (unsigned int)f2bf(lo) | ((unsigned int)f2bf(hi) << 16);
    }
    size_t base = ((size_t)(n * 132 + oy + 2) * 132 + ox + 2) * 32;
    uint4* dst = (uint4*)(h1p + base);
    dst[0] = make_uint4(u[0], u[1], u[2], u[3]);
    dst[1] = make_uint4(u[4], u[5], u[6], u[7]);
    dst[2] = make_uint4(u[8], u[9], u[10], u[11]);
    dst[3] = make_uint4(u[12], u[13], u[14], u[15]);
}

// conv2: h1p -> h2p via MFMA. Wave-pair splits co (16 each); wave tile = 64 px row.
// A frag: lane l holds A[m=l&15][k=(l>>4)*8+j] (pixel m, ci k). B preloaded: 25 taps x 4 VGPR.
// D: row(pixel)=(l>>4)*4+reg, col(co)=l&15.  grid (16,64), block 256.
__global__ __launch_bounds__(256) void conv2_mfma(const unsigned short* __restrict__ h1p,
                                                  const short* __restrict__ B,
                                                  const float* __restrict__ bias,
                                                  unsigned short* __restrict__ h2p) {
    const int tid = threadIdx.x;
    const int lane = tid & 63;
    const int w = tid >> 6;
    const int n = blockIdx.y;
    const int cohalf = w & 1;
    const int ml = lane & 15;
    const int kg = lane >> 4;

    bf16x8 bfrag[25];
    #pragma unroll
    for (int t = 0; t < 25; ++t)
        bfrag[t] = *(const bf16x8*)(B + ((t * 32 + cohalf * 16 + ml) * 32 + kg * 8));
    const float bia = bias[cohalf * 16 + ml];
    const int co = cohalf * 16 + ml;

    for (int it = 0; it < 2; ++it) {
        const int oy = blockIdx.x * 4 + (w >> 1) * 2 + it;   // 0..63
        f32x4 acc[4];
        #pragma unroll
        for (int t = 0; t < 4; ++t) acc[t] = (f32x4){bia, bia, bia, bia};
        #pragma unroll
        for (int kh = 0; kh < 5; ++kh) {
            // padded input row: 2*oy-2+kh + 2 = 2*oy+kh
            const unsigned short* rowbase = h1p + (size_t)(n * 132 + 2 * oy + kh) * (132 * 32);
            #pragma unroll
            for (int kw = 0; kw < 5; ++kw) {
                bf16x8 af[4];
                #pragma unroll
                for (int t = 0; t < 4; ++t) {
                    const int ixp = 2 * (16 * t + ml) + kw;   // padded col
                    af[t] = *(const bf16x8*)(rowbase + ixp * 32 + kg * 8);
                }
                const int tap = kh * 5 + kw;
                #pragma unroll
                for (int t = 0; t < 4; ++t)
                    acc[t] = __builtin_amdgcn_mfma_f32_16x16x32_bf16(af[t], bfrag[tap], acc[t], 0, 0, 0);
            }
        }
        #pragma unroll
        for (int t = 0; t < 4; ++t) {
            #pragma unroll
            for (int r = 0; r < 4; ++r) {
                const int px = 16 * t + kg * 4 + r;
                h2p[((size_t)(n * 68 + oy + 2) * 68 + px + 2) * 32 + co] = f2bf(fmaxf(acc[t][r], 0.f));
            }
        }
    }
}

// xconv: depthwise per-sample k5. Block = (n, 8-row strip); LDS = 12 rows x 68 x 32ci bf16.
// Thread = (ci, x-octet): 64 accumulators, 11x LDS reuse. grid (64, 8).
__global__ __launch_bounds__(256) void xconv_kernel(const unsigned short* __restrict__ h2p,
                                                    const float* __restrict__ ker,
                                                    unsigned short* __restrict__ sap) {
    __shared__ __align__(16) unsigned short tile[12 * 68 * 32];
    const int tid = threadIdx.x;
    const int n = blockIdx.x;
    const int rb = blockIdx.y;
    const unsigned short* src = h2p + (size_t)(n * 68 + rb * 8) * (68 * 32);
    for (int i = tid; i < 3264; i += 256)            // 12*68*32/8 16B-chunks
        *(uint4*)(tile + i * 8) = *(const uint4*)(src + i * 8);
    const int ci = tid & 31, xg = tid >> 5;
    const float* kp = ker + (size_t)(n * 32 + ci) * 25;
    float k[25];
    #pragma unroll
    for (int t = 0; t < 25; ++t) k[t] = kp[t];
    __syncthreads();

    float acc[8][8];
    #pragma unroll
    for (int r = 0; r < 8; ++r)
        #pragma unroll
        for (int j = 0; j < 8; ++j) acc[r][j] = 0.f;

    #pragma unroll
    for (int ir = 0; ir < 12; ++ir) {
        float v[12];
        #pragma unroll
        for (int t = 0; t < 12; ++t)
            v[t] = bf2f(tile[(ir * 68 + xg * 8 + t) * 32 + ci]);
        #pragma unroll
        for (int kh = 0; kh < 5; ++kh) {
            const int r = ir - kh;
            if (r >= 0 && r < 8) {
                #pragma unroll
                for (int j = 0; j < 8; ++j) {
                    float s = acc[r][j];
                    #pragma unroll
                    for (int kw = 0; kw < 5; ++kw) s += k[kh * 5 + kw] * v[j + kw];
                    acc[r][j] = s;
                }
            }
        }
    }
    #pragma unroll
    for (int r = 0; r < 8; ++r)
        #pragma unroll
        for (int j = 0; j < 8; ++j)
            sap[((size_t)(n * 66 + rb * 8 + r + 1) * 66 + xg * 8 + j + 1) * 32 + ci] = f2bf(acc[r][j]);
}

// mp1: sap -> fp via MFMA, k3 p1 (9 taps). Same skeleton as conv2. grid (16,64).
__global__ __launch_bounds__(256) void mp1_mfma(const unsigned short* __restrict__ sap,
                                                const short* __restrict__ B,
                                                const float* __restrict__ bias,
                                                unsigned short* __restrict__ fp) {
    const int tid = threadIdx.x;
    const int lane = tid & 63;
    const int w = tid >> 6;
    const int n = blockIdx.y;
    const int cohalf = w & 1;
    const int ml = lane & 15;
    const int kg = lane >> 4;

    bf16x8 bfrag[9];
    #pragma unroll
    for (int t = 0; t < 9; ++t)
        bfrag[t] = *(const bf16x8*)(B + ((t * 32 + cohalf * 16 + ml) * 32 + kg * 8));
    const float bia = bias[cohalf * 16 + ml];
    const int co = cohalf * 16 + ml;

    for (int it = 0; it < 2; ++it) {
        const int oy = blockIdx.x * 4 + (w >> 1) * 2 + it;
        f32x4 acc[4];
        #pragma unroll
        for (int t = 0; t < 4; ++t) acc[t] = (f32x4){bia, bia, bia, bia};
        #pragma unroll
        for (int kh = 0; kh < 3; ++kh) {
            const unsigned short* rowbase = sap + (size_t)(n * 66 + oy + kh) * (66 * 32);
            #pragma unroll
            for (int kw = 0; kw < 3; ++kw) {
                bf16x8 af[4];
                #pragma unroll
                for (int t = 0; t < 4; ++t)
                    af[t] = *(const bf16x8*)(rowbase + (16 * t + ml + kw) * 32 + kg * 8);
                #pragma unroll
                for (int t = 0; t < 4; ++t)
                    acc[t] = __builtin_amdgcn_mfma_f32_16x16x32_bf16(af[t], bfrag[kh * 3 + kw], acc[t], 0, 0, 0);
            }
        }
        #pragma unroll
        for (int t = 0; t < 4; ++t) {
            #pragma unroll
            for (int r = 0; r < 4; ++r) {
                const int px = 16 * t + kg * 4 + r;
                fp[((size_t)(n * 66 + oy + 1) * 66 + px + 1) * 32 + co] = f2bf(fmaxf(acc[t][r], 0.f));
            }
        }
    }
}

// mp2: fp bf16 NHWC -> flow f32 NCHW [64][2][64][64]. grid (16,64), block (64,4).
__global__ __launch_bounds__(256) void mp2_kernel(const unsigned short* __restrict__ fp,
                                                  const float* __restrict__ wp,
                                                  const float* __restrict__ bias,
                                                  float* __restrict__ out) {
    const int ox = threadIdx.x;
    const int oy = blockIdx.x * 4 + threadIdx.y;
    const int n = blockIdx.y;
    float a0 = bias[0], a1 = bias[1];
    #pragma unroll
    for (int kh = 0; kh < 3; ++kh) {
        const unsigned short* rowp = fp + (size_t)(n * 66 + oy + kh) * (66 * 32);
        #pragma unroll
        for (int kw = 0; kw < 3; ++kw) {
            const unsigned short* p = rowp + (ox + kw) * 32;
            const float* wt = wp + (kh * 3 + kw) * 64;
            #pragma unroll
            for (int q = 0; q < 4; ++q) {
                uint4 d = *(const uint4*)(p + q * 8);
                unsigned int uu[4] = {d.x, d.y, d.z, d.w};
                #pragma unroll
                for (int e = 0; e < 4; ++e) {
                    float v0 = __uint_as_float(uu[e] << 16);
                    float v1 = __uint_as_float(uu[e] & 0xFFFF0000u);
                    int ci = q * 8 + e * 2;
                    a0 += wt[ci * 2] * v0 + wt[(ci + 1) * 2] * v1;
                    a1 += wt[ci * 2 + 1] * v0 + wt[(ci + 1) * 2 + 1] * v1;
                }
            }
        }
    }
    size_t base = (size_t)n * 8192 + (size_t)oy * 64 + ox;
    out[base] = a0;
    out[base + 4096] = a1;
}

extern "C" void kernel_launch(void* const* d_in, const int* in_sizes, int n_in,
                              void* d_out, int out_size, void* d_ws, size_t ws_size,
                              hipStream_t stream) {
    (void)in_sizes; (void)n_in; (void)out_size; (void)ws_size;
    const float* images  = (const float*)d_in[0];
    const float* actions = (const float*)d_in[1];
    const float* pe_w1   = (const float*)d_in[2];
    const float* pe_b1   = (const float*)d_in[3];
    const float* pe_w2   = (const float*)d_in[4];
    const float* pe_b2   = (const float*)d_in[5];
    const float* ae_w1   = (const float*)d_in[6];
    const float* ae_b1   = (const float*)d_in[7];
    const float* ae_w2   = (const float*)d_in[8];
    const float* ae_b2   = (const float*)d_in[9];
    const float* mp_w1   = (const float*)d_in[10];
    const float* mp_b1   = (const float*)d_in[11];
    const float* mp_w2   = (const float*)d_in[12];
    const float* mp_b2   = (const float*)d_in[13];
    float* out = (float*)d_out;

    char* ws = (char*)d_ws;
    float* a_ker          = (float*)(ws + 0);               // 64*800*4 = 204800
    float* w1T            = (float*)(ws + 204800);          // 9600
    unsigned short* B2    = (unsigned short*)(ws + 214400); // 51200
    unsigned short* Bm1   = (unsigned short*)(ws + 265600); // 18432
    float* w2p            = (float*)(ws + 284032);          // 2304
    unsigned short* h1p   = (unsigned short*)(ws + 524288);                 // 64*132*132*32*2 = 71368704
    unsigned short* h2p   = (unsigned short*)(ws + 71892992);               // 64*68*68*32*2   = 18939904
    unsigned short* sap   = (unsigned short*)(ws + 90832896);               // 64*66*66*32*2   = 17842176
    unsigned short* fpb   = (unsigned short*)(ws + 108675072);              // 17842176 -> end 126517248

    zero_border_kernel<<<64 * 132, 64, 0, stream>>>((unsigned int*)h1p, 132, 2);
    zero_border_kernel<<<64 * 68, 64, 0, stream>>>((unsigned int*)h2p, 68, 2);
    zero_border_kernel<<<64 * 66, 64, 0, stream>>>((unsigned int*)sap, 66, 1);
    zero_border_kernel<<<64 * 66, 64, 0, stream>>>((unsigned int*)fpb, 66, 1);

    repack_conv1<<<10, 256, 0, stream>>>(pe_w1, w1T);
    repack_conv2<<<100, 256, 0, stream>>>(pe_w2, B2);
    repack_mp1<<<36, 256, 0, stream>>>(mp_w1, Bm1);
    repack_mp2<<<3, 256, 0, stream>>>(mp_w2, w2p);

    mlp_kernel<<<dim3(4, 64), 256, 0, stream>>>(actions, ae_w1, ae_b1, ae_w2, ae_b2, a_ker);
    conv1_kernel<<<dim3(64, 64), dim3(128, 2), 0, stream>>>(images, w1T, pe_b1, h1p);
    conv2_mfma<<<dim3(16, 64), 256, 0, stream>>>(h1p, (const short*)B2, pe_b2, h2p);
    xconv_kernel<<<dim3(64, 8), 256, 0, stream>>>(h2p, a_ker, sap);
    mp1_mfma<<<dim3(16, 64), 256, 0, stream>>>(sap, (const short*)Bm1, mp_b1, fpb);
    mp2_kernel<<<dim3(16, 64), dim3(64, 4), 0, stream>>>(fpb, w2p, mp_b2, out);
}

// Round 4
// 341.315 us; speedup vs baseline: 3.4104x; 1.1041x over previous
//
#include <hip/hip_runtime.h>

// Pipeline (activations NHWC bf16, zero-padded borders, rebuilt every launch):
//  images [64,256,256,3] f32 NHWC
//  pad_img: -> imgp [64,260,264,4] bf16 (pad 2, ch3=0)
//  conv1 (MFMA): 3->32 k5 s2 p2 relu -> h1p [64,132,132,32] bf16 (pad 2)
//        K=32 = 2px x 4ch per lane-group; one MFMA per y-tap covers all 5 x-taps
//  conv2 (MFMA): 32->32 k5 s2 p2 relu -> h2p [64,68,68,32] bf16 (pad 2)
//  MLP -> per-sample kernels [64,32,25] f32
//  xconv (LDS fp32): depthwise k5 p2 -> sap [64,66,66,32] bf16 (pad 1)
//  mp1 (MFMA): 32->32 k3 p1 relu -> fp [64,66,66,32] bf16 (pad 1)
//  mp2 (MFMA, B cols 2/16 used): 32->2 k3 p1 -> flow [64,2,64,64] f32 (d_out)
// ws aliasing: imgp shares the h2p+sap region (dead after conv1); h2p/sap border
// zeroing therefore runs AFTER conv1.

typedef __attribute__((ext_vector_type(8))) short bf16x8;
typedef __attribute__((ext_vector_type(4))) float f32x4;

__device__ __forceinline__ unsigned short f2bf(float f) {
    unsigned int u = __float_as_uint(f);
    u = (u + 0x7FFFu + ((u >> 16) & 1u)) >> 16;   // RNE
    return (unsigned short)u;
}
__device__ __forceinline__ float bf2f(unsigned short h) {
    return __uint_as_float(((unsigned int)h) << 16);
}

// Zero the pad border of a [64][R][R][32] bf16 tensor (viewed as uint, 16 uints/cell).
__global__ __launch_bounds__(64) void zero_border_kernel(unsigned int* t, int R, int pad) {
    int row = blockIdx.x % R;
    int n   = blockIdx.x / R;
    int tid = threadIdx.x;
    unsigned int* rp = t + (size_t)(n * R + row) * R * 16;
    if (row < pad || row >= R - pad) {
        for (int i = tid; i < R * 16; i += 64) rp[i] = 0u;
    } else {
        for (int i = tid; i < pad * 16; i += 64) {
            rp[i] = 0u;
            rp[(size_t)(R - pad) * 16 + i] = 0u;
        }
    }
}

// img f32 NHWC -> imgp bf16 [64][260][264][4] (pad 2 each side, ch3 = 0)
__global__ __launch_bounds__(256) void pad_img_kernel(const float* __restrict__ img,
                                                      unsigned short* __restrict__ imgp) {
    const int py = blockIdx.x % 260;
    const int n  = blockIdx.x / 260;
    const int iy = py - 2;
    const bool rowok = (iy >= 0) && (iy < 256);
    const float* srow = img + ((size_t)n * 256 + (rowok ? iy : 0)) * 768;
    unsigned short* drow = imgp + (size_t)(n * 260 + py) * 1056;
    for (int s = threadIdx.x; s < 1056; s += 256) {
        int px = s >> 2, c = s & 3;
        int ix = px - 2;
        float v = 0.f;
        if (rowok && c < 3 && ix >= 0 && ix < 256) v = srow[ix * 3 + c];
        drow[s] = f2bf(v);
    }
}

// pe_w1 [32][3][5][5] f32 -> B1 bf16 [kh][co][k=32], k = dx*4+c (dx<5,c<3 real)
__global__ __launch_bounds__(256) void repack_conv1b(const float* __restrict__ src, unsigned short* __restrict__ dst) {
    int idx = blockIdx.x * 256 + threadIdx.x;
    if (idx >= 5120) return;
    int kh = idx / 1024, r = idx % 1024, o = r / 32, k = r % 32, dx = k >> 2, c = k & 3;
    float v = (dx < 5 && c < 3) ? src[o * 75 + c * 25 + kh * 5 + dx] : 0.f;
    dst[idx] = f2bf(v);
}
// pe_w2 [32][32][25] f32 -> B2 bf16 [(tap*32+co)*32+ci]
__global__ __launch_bounds__(256) void repack_conv2(const float* __restrict__ src, unsigned short* __restrict__ dst) {
    int idx = blockIdx.x * 256 + threadIdx.x;
    if (idx >= 25600) return;
    int co = idx / 800, r = idx % 800, ci = r / 25, tap = r % 25;
    dst[(tap * 32 + co) * 32 + ci] = f2bf(src[idx]);
}
// mp_w1 [32][32][9] f32 -> Bm1 bf16 [(tap*32+co)*32+ci]
__global__ __launch_bounds__(256) void repack_mp1(const float* __restrict__ src, unsigned short* __restrict__ dst) {
    int idx = blockIdx.x * 256 + threadIdx.x;
    if (idx >= 9216) return;
    int co = idx / 288, r = idx % 288, ci = r / 9, tap = r % 9;
    dst[(tap * 32 + co) * 32 + ci] = f2bf(src[idx]);
}
// mp_w2 [2][32][9] f32 -> Bm2 bf16 [tap][16co][32ci], co<2 real else 0
__global__ __launch_bounds__(256) void repack_mp2b(const float* __restrict__ src, unsigned short* __restrict__ dst) {
    int idx = blockIdx.x * 256 + threadIdx.x;
    if (idx >= 4608) return;
    int tap = idx / 512, r = idx % 512, co = r / 32, ci = r % 32;
    float v = (co < 2) ? src[co * 288 + ci * 9 + tap] : 0.f;
    dst[idx] = f2bf(v);
}

// Action MLP: actions[64,4] -> relu(256) -> 800; grid (4,64)
__global__ __launch_bounds__(256) void mlp_kernel(const float* __restrict__ actions,
                                                  const float* __restrict__ w1,
                                                  const float* __restrict__ b1,
                                                  const float* __restrict__ w2,
                                                  const float* __restrict__ b2,
                                                  float* __restrict__ aout) {
    int n = blockIdx.y;
    int t = threadIdx.x;
    __shared__ float hid[256];
    float a0 = actions[n * 4 + 0], a1 = actions[n * 4 + 1];
    float a2 = actions[n * 4 + 2], a3 = actions[n * 4 + 3];
    float acc = b1[t];
    acc += a0 * w1[0 * 256 + t] + a1 * w1[1 * 256 + t] +
           a2 * w1[2 * 256 + t] + a3 * w1[3 * 256 + t];
    hid[t] = fmaxf(acc, 0.0f);
    __syncthreads();
    int o = blockIdx.x * 200 + t;
    if (t < 200) {
        float s = b2[o];
        #pragma unroll 4
        for (int i = 0; i < 256; ++i) s += hid[i] * w2[i * 800 + o];
        aout[n * 800 + o] = s;
    }
}

// conv1 MFMA: imgp -> h1p. Wave = one output row (8 x-tiles of 16px) x 16 co.
// A[m][k]: k = dx*4+c relative to patch start (padded px0 = 2*m'); one 16B load
// per (tile, y-tap) covers dx={2kg,2kg+1}, c=0..3. grid (64,64), block 256.
__global__ __launch_bounds__(256) void conv1_mfma(const unsigned short* __restrict__ imgp,
                                                  const short* __restrict__ B1,
                                                  const float* __restrict__ bias,
                                                  unsigned short* __restrict__ h1p) {
    const int tid = threadIdx.x;
    const int lane = tid & 63;
    const int w = tid >> 6;
    const int n = blockIdx.y;
    const int cohalf = w & 1;
    const int oy = blockIdx.x * 2 + (w >> 1);     // 0..127
    const int ml = lane & 15;
    const int kg = lane >> 4;

    bf16x8 bfrag[5];
    #pragma unroll
    for (int kh = 0; kh < 5; ++kh)
        bfrag[kh] = *(const bf16x8*)(B1 + ((kh * 32 + cohalf * 16 + ml) * 32 + kg * 8));
    const float bia = bias[cohalf * 16 + ml];
    const int co = cohalf * 16 + ml;

    f32x4 acc[8];
    #pragma unroll
    for (int t = 0; t < 8; ++t) acc[t] = (f32x4){bia, bia, bia, bia};

    #pragma unroll
    for (int kh = 0; kh < 5; ++kh) {
        const unsigned short* rowbase = imgp + (size_t)(n * 260 + 2 * oy + kh) * 1056;
        #pragma unroll
        for (int t = 0; t < 8; ++t) {
            const int px0 = 2 * (16 * t + ml) + 2 * kg;   // padded x of this K-slice
            bf16x8 af = *(const bf16x8*)(rowbase + px0 * 4);
            acc[t] = __builtin_amdgcn_mfma_f32_16x16x32_bf16(af, bfrag[kh], acc[t], 0, 0, 0);
        }
    }
    #pragma unroll
    for (int t = 0; t < 8; ++t) {
        #pragma unroll
        for (int r = 0; r < 4; ++r) {
            const int px = 16 * t + kg * 4 + r;
            h1p[((size_t)(n * 132 + oy + 2) * 132 + px + 2) * 32 + co] = f2bf(fmaxf(acc[t][r], 0.f));
        }
    }
}

// conv2: h1p -> h2p via MFMA. grid (16,64), block 256.
__global__ __launch_bounds__(256) void conv2_mfma(const unsigned short* __restrict__ h1p,
                                                  const short* __restrict__ B,
                                                  const float* __restrict__ bias,
                                                  unsigned short* __restrict__ h2p) {
    const int tid = threadIdx.x;
    const int lane = tid & 63;
    const int w = tid >> 6;
    const int n = blockIdx.y;
    const int cohalf = w & 1;
    const int ml = lane & 15;
    const int kg = lane >> 4;

    bf16x8 bfrag[25];
    #pragma unroll
    for (int t = 0; t < 25; ++t)
        bfrag[t] = *(const bf16x8*)(B + ((t * 32 + cohalf * 16 + ml) * 32 + kg * 8));
    const float bia = bias[cohalf * 16 + ml];
    const int co = cohalf * 16 + ml;

    for (int it = 0; it < 2; ++it) {
        const int oy = blockIdx.x * 4 + (w >> 1) * 2 + it;   // 0..63
        f32x4 acc[4];
        #pragma unroll
        for (int t = 0; t < 4; ++t) acc[t] = (f32x4){bia, bia, bia, bia};
        #pragma unroll
        for (int kh = 0; kh < 5; ++kh) {
            const unsigned short* rowbase = h1p + (size_t)(n * 132 + 2 * oy + kh) * (132 * 32);
            #pragma unroll
            for (int kw = 0; kw < 5; ++kw) {
                bf16x8 af[4];
                #pragma unroll
                for (int t = 0; t < 4; ++t) {
                    const int ixp = 2 * (16 * t + ml) + kw;
                    af[t] = *(const bf16x8*)(rowbase + ixp * 32 + kg * 8);
                }
                const int tap = kh * 5 + kw;
                #pragma unroll
                for (int t = 0; t < 4; ++t)
                    acc[t] = __builtin_amdgcn_mfma_f32_16x16x32_bf16(af[t], bfrag[tap], acc[t], 0, 0, 0);
            }
        }
        #pragma unroll
        for (int t = 0; t < 4; ++t) {
            #pragma unroll
            for (int r = 0; r < 4; ++r) {
                const int px = 16 * t + kg * 4 + r;
                h2p[((size_t)(n * 68 + oy + 2) * 68 + px + 2) * 32 + co] = f2bf(fmaxf(acc[t][r], 0.f));
            }
        }
    }
}

// xconv: depthwise per-sample k5. Block = (n, 8-row strip); LDS = 12 rows x 68 x 32ci.
__global__ __launch_bounds__(256) void xconv_kernel(const unsigned short* __restrict__ h2p,
                                                    const float* __restrict__ ker,
                                                    unsigned short* __restrict__ sap) {
    __shared__ __align__(16) unsigned short tile[12 * 68 * 32];
    const int tid = threadIdx.x;
    const int n = blockIdx.x;
    const int rb = blockIdx.y;
    const unsigned short* src = h2p + (size_t)(n * 68 + rb * 8) * (68 * 32);
    for (int i = tid; i < 3264; i += 256)
        *(uint4*)(tile + i * 8) = *(const uint4*)(src + i * 8);
    const int ci = tid & 31, xg = tid >> 5;
    const float* kp = ker + (size_t)(n * 32 + ci) * 25;
    float k[25];
    #pragma unroll
    for (int t = 0; t < 25; ++t) k[t] = kp[t];
    __syncthreads();

    float acc[8][8];
    #pragma unroll
    for (int r = 0; r < 8; ++r)
        #pragma unroll
        for (int j = 0; j < 8; ++j) acc[r][j] = 0.f;

    #pragma unroll
    for (int ir = 0; ir < 12; ++ir) {
        float v[12];
        #pragma unroll
        for (int t = 0; t < 12; ++t)
            v[t] = bf2f(tile[(ir * 68 + xg * 8 + t) * 32 + ci]);
        #pragma unroll
        for (int kh = 0; kh < 5; ++kh) {
            const int r = ir - kh;
            if (r >= 0 && r < 8) {
                #pragma unroll
                for (int j = 0; j < 8; ++j) {
                    float s = acc[r][j];
                    #pragma unroll
                    for (int kw = 0; kw < 5; ++kw) s += k[kh * 5 + kw] * v[j + kw];
                    acc[r][j] = s;
                }
            }
        }
    }
    #pragma unroll
    for (int r = 0; r < 8; ++r)
        #pragma unroll
        for (int j = 0; j < 8; ++j)
            sap[((size_t)(n * 66 + rb * 8 + r + 1) * 66 + xg * 8 + j + 1) * 32 + ci] = f2bf(acc[r][j]);
}

// mp1: sap -> fp via MFMA, k3 p1. grid (16,64).
__global__ __launch_bounds__(256) void mp1_mfma(const unsigned short* __restrict__ sap,
                                                const short* __restrict__ B,
                                                const float* __restrict__ bias,
                                                unsigned short* __restrict__ fp) {
    const int tid = threadIdx.x;
    const int lane = tid & 63;
    const int w = tid >> 6;
    const int n = blockIdx.y;
    const int cohalf = w & 1;
    const int ml = lane & 15;
    const int kg = lane >> 4;

    bf16x8 bfrag[9];
    #pragma unroll
    for (int t = 0; t < 9; ++t)
        bfrag[t] = *(const bf16x8*)(B + ((t * 32 + cohalf * 16 + ml) * 32 + kg * 8));
    const float bia = bias[cohalf * 16 + ml];
    const int co = cohalf * 16 + ml;

    for (int it = 0; it < 2; ++it) {
        const int oy = blockIdx.x * 4 + (w >> 1) * 2 + it;
        f32x4 acc[4];
        #pragma unroll
        for (int t = 0; t < 4; ++t) acc[t] = (f32x4){bia, bia, bia, bia};
        #pragma unroll
        for (int kh = 0; kh < 3; ++kh) {
            const unsigned short* rowbase = sap + (size_t)(n * 66 + oy + kh) * (66 * 32);
            #pragma unroll
            for (int kw = 0; kw < 3; ++kw) {
                bf16x8 af[4];
                #pragma unroll
                for (int t = 0; t < 4; ++t)
                    af[t] = *(const bf16x8*)(rowbase + (16 * t + ml + kw) * 32 + kg * 8);
                #pragma unroll
                for (int t = 0; t < 4; ++t)
                    acc[t] = __builtin_amdgcn_mfma_f32_16x16x32_bf16(af[t], bfrag[kh * 3 + kw], acc[t], 0, 0, 0);
            }
        }
        #pragma unroll
        for (int t = 0; t < 4; ++t) {
            #pragma unroll
            for (int r = 0; r < 4; ++r) {
                const int px = 16 * t + kg * 4 + r;
                fp[((size_t)(n * 66 + oy + 1) * 66 + px + 1) * 32 + co] = f2bf(fmaxf(acc[t][r], 0.f));
            }
        }
    }
}

// mp2 MFMA: fp -> flow f32 NCHW. B has 16 cols, only co 0/1 nonzero. grid (16,64).
__global__ __launch_bounds__(256) void mp2_mfma(const unsigned short* __restrict__ fpb,
                                                const short* __restrict__ B,
                                                const float* __restrict__ bias,
                                                float* __restrict__ out) {
    const int tid = threadIdx.x;
    const int lane = tid & 63;
    const int w = tid >> 6;
    const int n = blockIdx.y;
    const int oy = blockIdx.x * 4 + w;    // 0..63
    const int ml = lane & 15;
    const int kg = lane >> 4;

    bf16x8 bfrag[9];
    #pragma unroll
    for (int t = 0; t < 9; ++t)
        bfrag[t] = *(const bf16x8*)(B + ((t * 16 + ml) * 32 + kg * 8));
    const float bia = (ml < 2) ? bias[ml] : 0.f;

    f32x4 acc[4];
    #pragma unroll
    for (int t = 0; t < 4; ++t) acc[t] = (f32x4){bia, bia, bia, bia};

    #pragma unroll
    for (int kh = 0; kh < 3; ++kh) {
        const unsigned short* rowbase = fpb + (size_t)(n * 66 + oy + kh) * (66 * 32);
        #pragma unroll
        for (int kw = 0; kw < 3; ++kw) {
            #pragma unroll
            for (int t = 0; t < 4; ++t) {
                bf16x8 af = *(const bf16x8*)(rowbase + (16 * t + ml + kw) * 32 + kg * 8);
                acc[t] = __builtin_amdgcn_mfma_f32_16x16x32_bf16(af, bfrag[kh * 3 + kw], acc[t], 0, 0, 0);
            }
        }
    }
    if (ml < 2) {
        #pragma unroll
        for (int t = 0; t < 4; ++t) {
            #pragma unroll
            for (int r = 0; r < 4; ++r) {
                const int px = 16 * t + kg * 4 + r;
                out[(size_t)n * 8192 + (size_t)ml * 4096 + (size_t)oy * 64 + px] = acc[t][r];
            }
        }
    }
}

extern "C" void kernel_launch(void* const* d_in, const int* in_sizes, int n_in,
                              void* d_out, int out_size, void* d_ws, size_t ws_size,
                              hipStream_t stream) {
    (void)in_sizes; (void)n_in; (void)out_size; (void)ws_size;
    const float* images  = (const float*)d_in[0];
    const float* actions = (const float*)d_in[1];
    const float* pe_w1   = (const float*)d_in[2];
    const float* pe_b1   = (const float*)d_in[3];
    const float* pe_w2   = (const float*)d_in[4];
    const float* pe_b2   = (const float*)d_in[5];
    const float* ae_w1   = (const float*)d_in[6];
    const float* ae_b1   = (const float*)d_in[7];
    const float* ae_w2   = (const float*)d_in[8];
    const float* ae_b2   = (const float*)d_in[9];
    const float* mp_w1   = (const float*)d_in[10];
    const float* mp_b1   = (const float*)d_in[11];
    const float* mp_w2   = (const float*)d_in[12];
    const float* mp_b2   = (const float*)d_in[13];
    float* out = (float*)d_out;

    char* ws = (char*)d_ws;
    float* a_ker          = (float*)(ws + 0);               // 204800
    unsigned short* B1    = (unsigned short*)(ws + 204800); // 10240
    unsigned short* B2    = (unsigned short*)(ws + 215040); // 51200
    unsigned short* Bm1   = (unsigned short*)(ws + 266240); // 18432
    unsigned short* Bm2   = (unsigned short*)(ws + 284672); // 9216
    unsigned short* h1p   = (unsigned short*)(ws + 524288);    // 71,368,704 -> 71,892,992
    unsigned short* imgp  = (unsigned short*)(ws + 71892992);  // 35,143,680 -> 107,036,672 (dead after conv1)
    unsigned short* h2p   = (unsigned short*)(ws + 71892992);  // 18,939,904 -> 90,832,896 (aliases imgp)
    unsigned short* sap   = (unsigned short*)(ws + 90832896);  // 17,842,176 -> 108,675,072 (aliases imgp tail)
    unsigned short* fpb   = (unsigned short*)(ws + 108675072); // 17,842,176 -> 126,517,248

    repack_conv1b<<<20, 256, 0, stream>>>(pe_w1, B1);
    repack_conv2<<<100, 256, 0, stream>>>(pe_w2, B2);
    repack_mp1<<<36, 256, 0, stream>>>(mp_w1, Bm1);
    repack_mp2b<<<18, 256, 0, stream>>>(mp_w2, Bm2);
    mlp_kernel<<<dim3(4, 64), 256, 0, stream>>>(actions, ae_w1, ae_b1, ae_w2, ae_b2, a_ker);

    zero_border_kernel<<<64 * 132, 64, 0, stream>>>((unsigned int*)h1p, 132, 2);
    zero_border_kernel<<<64 * 66, 64, 0, stream>>>((unsigned int*)fpb, 66, 1);

    pad_img_kernel<<<64 * 260, 256, 0, stream>>>(images, imgp);
    conv1_mfma<<<dim3(64, 64), 256, 0, stream>>>(imgp, (const short*)B1, pe_b1, h1p);

    // imgp dead from here; its region is reused by h2p/sap
    zero_border_kernel<<<64 * 68, 64, 0, stream>>>((unsigned int*)h2p, 68, 2);
    zero_border_kernel<<<64 * 66, 64, 0, stream>>>((unsigned int*)sap, 66, 1);

    conv2_mfma<<<dim3(16, 64), 256, 0, stream>>>(h1p, (const short*)B2, pe_b2, h2p);
    xconv_kernel<<<dim3(64, 8), 256, 0, stream>>>(h2p, a_ker, sap);
    mp1_mfma<<<dim3(16, 64), 256, 0, stream>>>(sap, (const short*)Bm1, mp_b1, fpb);
    mp2_mfma<<<dim3(16, 64), 256, 0, stream>>>(fpb, (const short*)Bm2, mp_b2, out);
}

// Round 5
// 296.126 us; speedup vs baseline: 3.9308x; 1.1526x over previous
//
#include <hip/hip_runtime.h>

// Pipeline (activations NHWC bf16, zero-padded borders, rebuilt every launch):
//  pad_img: images f32 -> imgp [64,260,264,4] bf16 (pad 2, ch3=0)
//  conv1 (MFMA 16x16x32): 3->32 k5 s2 p2 relu -> h1p [64,132,132,32] bf16 (pad 2)
//  conv2 (MFMA 32x32x16, B staged per-kh in LDS): -> h2p [64,68,68,32] bf16 (pad 2)
//  MLP -> per-sample kernels [64,32,25] f32
//  xconv (LDS fp32): depthwise k5 p2 -> sap [64,66,66,32] bf16 (pad 1)
//  mp1 (MFMA 32x32x16, B in LDS): 32->32 k3 p1 relu -> fp [64,66,66,32] bf16 (pad 1)
//  mp2 (MFMA 16x16x32, B cols 2/16 used): 32->2 k3 p1 -> flow f32 (d_out)
// ws aliasing: imgp shares h2p+sap region (dead after conv1).

typedef __attribute__((ext_vector_type(8))) short bf16x8;
typedef __attribute__((ext_vector_type(4))) float f32x4;
typedef __attribute__((ext_vector_type(16))) float f32x16;

__device__ __forceinline__ unsigned short f2bf(float f) {
    unsigned int u = __float_as_uint(f);
    u = (u + 0x7FFFu + ((u >> 16) & 1u)) >> 16;   // RNE
    return (unsigned short)u;
}
__device__ __forceinline__ float bf2f(unsigned short h) {
    return __uint_as_float(((unsigned int)h) << 16);
}

// Zero the pad border of a [64][R][R][32] bf16 tensor (viewed as uint, 16 uints/cell).
__global__ __launch_bounds__(64) void zero_border_kernel(unsigned int* t, int R, int pad) {
    int row = blockIdx.x % R;
    int n   = blockIdx.x / R;
    int tid = threadIdx.x;
    unsigned int* rp = t + (size_t)(n * R + row) * R * 16;
    if (row < pad || row >= R - pad) {
        for (int i = tid; i < R * 16; i += 64) rp[i] = 0u;
    } else {
        for (int i = tid; i < pad * 16; i += 64) {
            rp[i] = 0u;
            rp[(size_t)(R - pad) * 16 + i] = 0u;
        }
    }
}

// img f32 NHWC -> imgp bf16 [64][260][264][4] (pad 2 each side, ch3 = 0)
__global__ __launch_bounds__(256) void pad_img_kernel(const float* __restrict__ img,
                                                      unsigned short* __restrict__ imgp) {
    const int py = blockIdx.x % 260;
    const int n  = blockIdx.x / 260;
    const int iy = py - 2;
    const bool rowok = (iy >= 0) && (iy < 256);
    const float* srow = img + ((size_t)n * 256 + (rowok ? iy : 0)) * 768;
    unsigned short* drow = imgp + (size_t)(n * 260 + py) * 1056;
    for (int s = threadIdx.x; s < 1056; s += 256) {
        int px = s >> 2, c = s & 3;
        int ix = px - 2;
        float v = 0.f;
        if (rowok && c < 3 && ix >= 0 && ix < 256) v = srow[ix * 3 + c];
        drow[s] = f2bf(v);
    }
}

// pe_w1 [32][3][5][5] f32 -> B1 bf16 [kh][co][k=32], k = dx*4+c (dx<5,c<3 real)
__global__ __launch_bounds__(256) void repack_conv1b(const float* __restrict__ src, unsigned short* __restrict__ dst) {
    int idx = blockIdx.x * 256 + threadIdx.x;
    if (idx >= 5120) return;
    int kh = idx / 1024, r = idx % 1024, o = r / 32, k = r % 32, dx = k >> 2, c = k & 3;
    float v = (dx < 5 && c < 3) ? src[o * 75 + c * 25 + kh * 5 + dx] : 0.f;
    dst[idx] = f2bf(v);
}
// pe_w2 [32][32][25] f32 -> B2 bf16 [(tap*32+co)*32+ci]
__global__ __launch_bounds__(256) void repack_conv2(const float* __restrict__ src, unsigned short* __restrict__ dst) {
    int idx = blockIdx.x * 256 + threadIdx.x;
    if (idx >= 25600) return;
    int co = idx / 800, r = idx % 800, ci = r / 25, tap = r % 25;
    dst[(tap * 32 + co) * 32 + ci] = f2bf(src[idx]);
}
// mp_w1 [32][32][9] f32 -> Bm1 bf16 [(tap*32+co)*32+ci]
__global__ __launch_bounds__(256) void repack_mp1(const float* __restrict__ src, unsigned short* __restrict__ dst) {
    int idx = blockIdx.x * 256 + threadIdx.x;
    if (idx >= 9216) return;
    int co = idx / 288, r = idx % 288, ci = r / 9, tap = r % 9;
    dst[(tap * 32 + co) * 32 + ci] = f2bf(src[idx]);
}
// mp_w2 [2][32][9] f32 -> Bm2 bf16 [tap][16co][32ci], co<2 real else 0
__global__ __launch_bounds__(256) void repack_mp2b(const float* __restrict__ src, unsigned short* __restrict__ dst) {
    int idx = blockIdx.x * 256 + threadIdx.x;
    if (idx >= 4608) return;
    int tap = idx / 512, r = idx % 512, co = r / 32, ci = r % 32;
    float v = (co < 2) ? src[co * 288 + ci * 9 + tap] : 0.f;
    dst[idx] = f2bf(v);
}

// Action MLP: actions[64,4] -> relu(256) -> 800; grid (4,64)
__global__ __launch_bounds__(256) void mlp_kernel(const float* __restrict__ actions,
                                                  const float* __restrict__ w1,
                                                  const float* __restrict__ b1,
                                                  const float* __restrict__ w2,
                                                  const float* __restrict__ b2,
                                                  float* __restrict__ aout) {
    int n = blockIdx.y;
    int t = threadIdx.x;
    __shared__ float hid[256];
    float a0 = actions[n * 4 + 0], a1 = actions[n * 4 + 1];
    float a2 = actions[n * 4 + 2], a3 = actions[n * 4 + 3];
    float acc = b1[t];
    acc += a0 * w1[0 * 256 + t] + a1 * w1[1 * 256 + t] +
           a2 * w1[2 * 256 + t] + a3 * w1[3 * 256 + t];
    hid[t] = fmaxf(acc, 0.0f);
    __syncthreads();
    int o = blockIdx.x * 200 + t;
    if (t < 200) {
        float s = b2[o];
        #pragma unroll 4
        for (int i = 0; i < 256; ++i) s += hid[i] * w2[i * 800 + o];
        aout[n * 800 + o] = s;
    }
}

// conv1 MFMA: imgp -> h1p. grid (64,64), block 256.
__global__ __launch_bounds__(256) void conv1_mfma(const unsigned short* __restrict__ imgp,
                                                  const short* __restrict__ B1,
                                                  const float* __restrict__ bias,
                                                  unsigned short* __restrict__ h1p) {
    const int tid = threadIdx.x;
    const int lane = tid & 63;
    const int w = tid >> 6;
    const int n = blockIdx.y;
    const int cohalf = w & 1;
    const int oy = blockIdx.x * 2 + (w >> 1);     // 0..127
    const int ml = lane & 15;
    const int kg = lane >> 4;

    bf16x8 bfrag[5];
    #pragma unroll
    for (int kh = 0; kh < 5; ++kh)
        bfrag[kh] = *(const bf16x8*)(B1 + ((kh * 32 + cohalf * 16 + ml) * 32 + kg * 8));
    const float bia = bias[cohalf * 16 + ml];
    const int co = cohalf * 16 + ml;

    f32x4 acc[8];
    #pragma unroll
    for (int t = 0; t < 8; ++t) acc[t] = (f32x4){bia, bia, bia, bia};

    #pragma unroll
    for (int kh = 0; kh < 5; ++kh) {
        const unsigned short* rowbase = imgp + (size_t)(n * 260 + 2 * oy + kh) * 1056;
        #pragma unroll
        for (int t = 0; t < 8; ++t) {
            const int px0 = 2 * (16 * t + ml) + 2 * kg;
            bf16x8 af = *(const bf16x8*)(rowbase + px0 * 4);
            acc[t] = __builtin_amdgcn_mfma_f32_16x16x32_bf16(af, bfrag[kh], acc[t], 0, 0, 0);
        }
    }
    #pragma unroll
    for (int t = 0; t < 8; ++t) {
        #pragma unroll
        for (int r = 0; r < 4; ++r) {
            const int px = 16 * t + kg * 4 + r;
            h1p[((size_t)(n * 132 + oy + 2) * 132 + px + 2) * 32 + co] = f2bf(fmaxf(acc[t][r], 0.f));
        }
    }
}

// conv2 via 32x32x16 MFMA. Wave = 32px x 32co; B staged per-kh in LDS (5 taps,
// rows padded to 40 elems = 80B for bank spread + 16B alignment). grid (32,64).
__global__ __launch_bounds__(256, 6) void conv2_mfma32(const unsigned short* __restrict__ h1p,
                                                       const unsigned int* __restrict__ B,
                                                       const float* __restrict__ bias,
                                                       unsigned short* __restrict__ h2p) {
    __shared__ unsigned int Bs[5 * 32 * 20];       // 5 taps x 32 co x 40 bf16 = 12800 B
    const int tid = threadIdx.x;
    const int lane = tid & 63;
    const int w = tid >> 6;
    const int n = blockIdx.y;
    const int oy = blockIdx.x * 2 + (w >> 1);      // 0..63
    const int x0 = (w & 1) * 32;
    const int co = lane & 31;
    const int kgrp = lane >> 5;                    // 0/1

    const float bia = bias[co];
    f32x16 acc;
    #pragma unroll
    for (int r = 0; r < 16; ++r) acc[r] = bia;

    const unsigned short* bbase = (const unsigned short*)Bs + co * 40 + kgrp * 8;
    const int px0 = 2 * (x0 + co);                 // padded x base (stride 2)

    for (int kh = 0; kh < 5; ++kh) {
        if (kh) __syncthreads();
        // stage taps kh*5 .. kh*5+4 : 2560 uints
        const unsigned int* src = B + kh * 2560;
        #pragma unroll
        for (int i = tid; i < 2560; i += 256) {
            int row = i >> 4, p = i & 15;
            Bs[row * 20 + p] = src[i];
        }
        __syncthreads();

        const unsigned short* rowbase = h1p + (size_t)(n * 132 + 2 * oy + kh) * (132 * 32) + kgrp * 8;
        #pragma unroll
        for (int kw = 0; kw < 5; ++kw) {
            bf16x8 a0 = *(const bf16x8*)(rowbase + (px0 + kw) * 32);
            bf16x8 a1 = *(const bf16x8*)(rowbase + (px0 + kw) * 32 + 16);
            bf16x8 b0 = *(const bf16x8*)(bbase + kw * (32 * 40));
            bf16x8 b1 = *(const bf16x8*)(bbase + kw * (32 * 40) + 16);
            acc = __builtin_amdgcn_mfma_f32_32x32x16_bf16(a0, b0, acc, 0, 0, 0);
            acc = __builtin_amdgcn_mfma_f32_32x32x16_bf16(a1, b1, acc, 0, 0, 0);
        }
    }
    #pragma unroll
    for (int r = 0; r < 16; ++r) {
        const int px = (r & 3) + 8 * (r >> 2) + 4 * kgrp;
        const int ox = x0 + px;
        h2p[((size_t)(n * 68 + oy + 2) * 68 + ox + 2) * 32 + co] = f2bf(fmaxf(acc[r], 0.f));
    }
}

// xconv: depthwise per-sample k5. Block = (n, 8-row strip); LDS = 12 rows x 68 x 32ci.
__global__ __launch_bounds__(256) void xconv_kernel(const unsigned short* __restrict__ h2p,
                                                    const float* __restrict__ ker,
                                                    unsigned short* __restrict__ sap) {
    __shared__ __align__(16) unsigned short tile[12 * 68 * 32];
    const int tid = threadIdx.x;
    const int n = blockIdx.x;
    const int rb = blockIdx.y;
    const unsigned short* src = h2p + (size_t)(n * 68 + rb * 8) * (68 * 32);
    for (int i = tid; i < 3264; i += 256)
        *(uint4*)(tile + i * 8) = *(const uint4*)(src + i * 8);
    const int ci = tid & 31, xg = tid >> 5;
    const float* kp = ker + (size_t)(n * 32 + ci) * 25;
    float k[25];
    #pragma unroll
    for (int t = 0; t < 25; ++t) k[t] = kp[t];
    __syncthreads();

    float acc[8][8];
    #pragma unroll
    for (int r = 0; r < 8; ++r)
        #pragma unroll
        for (int j = 0; j < 8; ++j) acc[r][j] = 0.f;

    #pragma unroll
    for (int ir = 0; ir < 12; ++ir) {
        float v[12];
        #pragma unroll
        for (int t = 0; t < 12; ++t)
            v[t] = bf2f(tile[(ir * 68 + xg * 8 + t) * 32 + ci]);
        #pragma unroll
        for (int kh = 0; kh < 5; ++kh) {
            const int r = ir - kh;
            if (r >= 0 && r < 8) {
                #pragma unroll
                for (int j = 0; j < 8; ++j) {
                    float s = acc[r][j];
                    #pragma unroll
                    for (int kw = 0; kw < 5; ++kw) s += k[kh * 5 + kw] * v[j + kw];
                    acc[r][j] = s;
                }
            }
        }
    }
    #pragma unroll
    for (int r = 0; r < 8; ++r)
        #pragma unroll
        for (int j = 0; j < 8; ++j)
            sap[((size_t)(n * 66 + rb * 8 + r + 1) * 66 + xg * 8 + j + 1) * 32 + ci] = f2bf(acc[r][j]);
}

// mp1 via 32x32x16 MFMA. All 9 taps staged once in LDS (23 KB). grid (32,64).
__global__ __launch_bounds__(256, 6) void mp1_mfma32(const unsigned short* __restrict__ sap,
                                                     const unsigned int* __restrict__ B,
                                                     const float* __restrict__ bias,
                                                     unsigned short* __restrict__ fp) {
    __shared__ unsigned int Bs[9 * 32 * 20];       // 9 taps x 32 co x 40 bf16 = 23040 B
    const int tid = threadIdx.x;
    #pragma unroll
    for (int i = tid; i < 4608; i += 256) {
        int row = i >> 4, p = i & 15;
        Bs[row * 20 + p] = B[i];
    }
    __syncthreads();

    const int lane = tid & 63;
    const int w = tid >> 6;
    const int n = blockIdx.y;
    const int oy = blockIdx.x * 2 + (w >> 1);      // 0..63
    const int x0 = (w & 1) * 32;
    const int co = lane & 31;
    const int kgrp = lane >> 5;

    const float bia = bias[co];
    f32x16 acc;
    #pragma unroll
    for (int r = 0; r < 16; ++r) acc[r] = bia;

    const unsigned short* bbase = (const unsigned short*)Bs + co * 40 + kgrp * 8;
    const int px0 = x0 + co;                       // padded x base (stride 1)

    #pragma unroll
    for (int kh = 0; kh < 3; ++kh) {
        const unsigned short* rowbase = sap + (size_t)(n * 66 + oy + kh) * (66 * 32) + kgrp * 8;
        #pragma unroll
        for (int kw = 0; kw < 3; ++kw) {
            const int tap = kh * 3 + kw;
            bf16x8 a0 = *(const bf16x8*)(rowbase + (px0 + kw) * 32);
            bf16x8 a1 = *(const bf16x8*)(rowbase + (px0 + kw) * 32 + 16);
            bf16x8 b0 = *(const bf16x8*)(bbase + tap * (32 * 40));
            bf16x8 b1 = *(const bf16x8*)(bbase + tap * (32 * 40) + 16);
            acc = __builtin_amdgcn_mfma_f32_32x32x16_bf16(a0, b0, acc, 0, 0, 0);
            acc = __builtin_amdgcn_mfma_f32_32x32x16_bf16(a1, b1, acc, 0, 0, 0);
        }
    }
    #pragma unroll
    for (int r = 0; r < 16; ++r) {
        const int px = (r & 3) + 8 * (r >> 2) + 4 * kgrp;
        const int ox = x0 + px;
        fp[((size_t)(n * 66 + oy + 1) * 66 + ox + 1) * 32 + co] = f2bf(fmaxf(acc[r], 0.f));
    }
}

// mp2 MFMA: fp -> flow f32 NCHW. B has 16 cols, only co 0/1 nonzero. grid (16,64).
__global__ __launch_bounds__(256) void mp2_mfma(const unsigned short* __restrict__ fpb,
                                                const short* __restrict__ B,
                                                const float* __restrict__ bias,
                                                float* __restrict__ out) {
    const int tid = threadIdx.x;
    const int lane = tid & 63;
    const int w = tid >> 6;
    const int n = blockIdx.y;
    const int oy = blockIdx.x * 4 + w;    // 0..63
    const int ml = lane & 15;
    const int kg = lane >> 4;

    bf16x8 bfrag[9];
    #pragma unroll
    for (int t = 0; t < 9; ++t)
        bfrag[t] = *(const bf16x8*)(B + ((t * 16 + ml) * 32 + kg * 8));
    const float bia = (ml < 2) ? bias[ml] : 0.f;

    f32x4 acc[4];
    #pragma unroll
    for (int t = 0; t < 4; ++t) acc[t] = (f32x4){bia, bia, bia, bia};

    #pragma unroll
    for (int kh = 0; kh < 3; ++kh) {
        const unsigned short* rowbase = fpb + (size_t)(n * 66 + oy + kh) * (66 * 32);
        #pragma unroll
        for (int kw = 0; kw < 3; ++kw) {
            #pragma unroll
            for (int t = 0; t < 4; ++t) {
                bf16x8 af = *(const bf16x8*)(rowbase + (16 * t + ml + kw) * 32 + kg * 8);
                acc[t] = __builtin_amdgcn_mfma_f32_16x16x32_bf16(af, bfrag[kh * 3 + kw], acc[t], 0, 0, 0);
            }
        }
    }
    if (ml < 2) {
        #pragma unroll
        for (int t = 0; t < 4; ++t) {
            #pragma unroll
            for (int r = 0; r < 4; ++r) {
                const int px = 16 * t + kg * 4 + r;
                out[(size_t)n * 8192 + (size_t)ml * 4096 + (size_t)oy * 64 + px] = acc[t][r];
            }
        }
    }
}

extern "C" void kernel_launch(void* const* d_in, const int* in_sizes, int n_in,
                              void* d_out, int out_size, void* d_ws, size_t ws_size,
                              hipStream_t stream) {
    (void)in_sizes; (void)n_in; (void)out_size; (void)ws_size;
    const float* images  = (const float*)d_in[0];
    const float* actions = (const float*)d_in[1];
    const float* pe_w1   = (const float*)d_in[2];
    const float* pe_b1   = (const float*)d_in[3];
    const float* pe_w2   = (const float*)d_in[4];
    const float* pe_b2   = (const float*)d_in[5];
    const float* ae_w1   = (const float*)d_in[6];
    const float* ae_b1   = (const float*)d_in[7];
    const float* ae_w2   = (const float*)d_in[8];
    const float* ae_b2   = (const float*)d_in[9];
    const float* mp_w1   = (const float*)d_in[10];
    const float* mp_b1   = (const float*)d_in[11];
    const float* mp_w2   = (const float*)d_in[12];
    const float* mp_b2   = (const float*)d_in[13];
    float* out = (float*)d_out;

    char* ws = (char*)d_ws;
    float* a_ker          = (float*)(ws + 0);               // 204800
    unsigned short* B1    = (unsigned short*)(ws + 204800); // 10240
    unsigned short* B2    = (unsigned short*)(ws + 215040); // 51200
    unsigned short* Bm1   = (unsigned short*)(ws + 266240); // 18432
    unsigned short* Bm2   = (unsigned short*)(ws + 284672); // 9216
    unsigned short* h1p   = (unsigned short*)(ws + 524288);    // 71,368,704 -> 71,892,992
    unsigned short* imgp  = (unsigned short*)(ws + 71892992);  // 35,143,680 (dead after conv1)
    unsigned short* h2p   = (unsigned short*)(ws + 71892992);  // 18,939,904 (aliases imgp)
    unsigned short* sap   = (unsigned short*)(ws + 90832896);  // 17,842,176 (aliases imgp tail)
    unsigned short* fpb   = (unsigned short*)(ws + 108675072); // 17,842,176 -> 126,517,248

    repack_conv1b<<<20, 256, 0, stream>>>(pe_w1, B1);
    repack_conv2<<<100, 256, 0, stream>>>(pe_w2, B2);
    repack_mp1<<<36, 256, 0, stream>>>(mp_w1, Bm1);
    repack_mp2b<<<18, 256, 0, stream>>>(mp_w2, Bm2);
    mlp_kernel<<<dim3(4, 64), 256, 0, stream>>>(actions, ae_w1, ae_b1, ae_w2, ae_b2, a_ker);

    zero_border_kernel<<<64 * 132, 64, 0, stream>>>((unsigned int*)h1p, 132, 2);
    zero_border_kernel<<<64 * 66, 64, 0, stream>>>((unsigned int*)fpb, 66, 1);

    pad_img_kernel<<<64 * 260, 256, 0, stream>>>(images, imgp);
    conv1_mfma<<<dim3(64, 64), 256, 0, stream>>>(imgp, (const short*)B1, pe_b1, h1p);

    // imgp dead from here; its region is reused by h2p/sap
    zero_border_kernel<<<64 * 68, 64, 0, stream>>>((unsigned int*)h2p, 68, 2);
    zero_border_kernel<<<64 * 66, 64, 0, stream>>>((unsigned int*)sap, 66, 1);

    conv2_mfma32<<<dim3(32, 64), 256, 0, stream>>>(h1p, (const unsigned int*)B2, pe_b2, h2p);
    xconv_kernel<<<dim3(64, 8), 256, 0, stream>>>(h2p, a_ker, sap);
    mp1_mfma32<<<dim3(32, 64), 256, 0, stream>>>(sap, (const unsigned int*)Bm1, mp_b1, fpb);
    mp2_mfma<<<dim3(16, 64), 256, 0, stream>>>(fpb, (const short*)Bm2, mp_b2, out);
}

// Round 6
// 288.009 us; speedup vs baseline: 4.0416x; 1.0282x over previous
//
#include <hip/hip_runtime.h>

// Pipeline (activations NHWC bf16, zero-padded borders, rebuilt every launch):
//  pad_img: images f32 -> imgp [64,260,264,4] bf16 (pad 2, ch3=0)
//  conv1 (MFMA 16x16x32, batched loads): 3->32 k5 s2 p2 relu -> h1p [64,132,132,32] bf16 (pad 2)
//  conv2 (MFMA 32x32x16, B per-kh in LDS, batched loads): -> h2p [64,68,68,32] bf16 (pad 2)
//  MLP -> per-sample kernels [64,32,25] f32
//  xconv (LDS fp32): depthwise k5 p2 -> sap [64,66,66,32] bf16 (pad 1)
//  mp1 (MFMA 32x32x16, B in LDS, batched): 32->32 k3 p1 relu -> fp [64,66,66,32] bf16 (pad 1)
//  mp2 (MFMA 16x16x32, batched): 32->2 k3 p1 -> flow f32 (d_out)
// ws aliasing: imgp shares h2p+sap region (dead after conv1).
// Key R6 change: source-level load batching (register arrays) so 10+ loads are
// in flight before each MFMA chain — R5 had VGPR=32 (zero prefetch headroom,
// every load's latency fully exposed; MfmaUtil 8%).

typedef __attribute__((ext_vector_type(8))) short bf16x8;
typedef __attribute__((ext_vector_type(4))) float f32x4;
typedef __attribute__((ext_vector_type(16))) float f32x16;

__device__ __forceinline__ unsigned short f2bf(float f) {
    unsigned int u = __float_as_uint(f);
    u = (u + 0x7FFFu + ((u >> 16) & 1u)) >> 16;   // RNE
    return (unsigned short)u;
}
__device__ __forceinline__ float bf2f(unsigned short h) {
    return __uint_as_float(((unsigned int)h) << 16);
}

// Zero pad borders of two [64][R][R][32] bf16 tensors (uint view, 16 uints/cell).
__global__ __launch_bounds__(64) void zero_border2(unsigned int* t0, int R0, int p0,
                                                   unsigned int* t1, int R1, int p1) {
    unsigned int* t = blockIdx.y ? t1 : t0;
    const int R = blockIdx.y ? R1 : R0;
    const int pad = blockIdx.y ? p1 : p0;
    const int row = blockIdx.x % R;
    const int n = blockIdx.x / R;
    if (n >= 64) return;
    const int tid = threadIdx.x;
    unsigned int* rp = t + (size_t)(n * R + row) * R * 16;
    if (row < pad || row >= R - pad) {
        for (int i = tid; i < R * 16; i += 64) rp[i] = 0u;
    } else {
        for (int i = tid; i < pad * 16; i += 64) {
            rp[i] = 0u;
            rp[(size_t)(R - pad) * 16 + i] = 0u;
        }
    }
}

// img f32 NHWC -> imgp bf16 [64][260][264][4] (pad 2 each side, ch3 = 0)
__global__ __launch_bounds__(256) void pad_img_kernel(const float* __restrict__ img,
                                                      unsigned short* __restrict__ imgp) {
    const int py = blockIdx.x % 260;
    const int n  = blockIdx.x / 260;
    const int iy = py - 2;
    const bool rowok = (iy >= 0) && (iy < 256);
    const float* srow = img + ((size_t)n * 256 + (rowok ? iy : 0)) * 768;
    unsigned short* drow = imgp + (size_t)(n * 260 + py) * 1056;
    for (int s = threadIdx.x; s < 1056; s += 256) {
        int px = s >> 2, c = s & 3;
        int ix = px - 2;
        float v = 0.f;
        if (rowok && c < 3 && ix >= 0 && ix < 256) v = srow[ix * 3 + c];
        drow[s] = f2bf(v);
    }
}

// All weight repacks in one kernel. Ranges:
//  [0,5120): pe_w1 [32][3][5][5] -> B1 [kh][co][k=32], k=dx*4+c (dx<5,c<3 real)
//  [5120,30720): pe_w2 [32][32][25] -> B2 [(tap*32+co)*32+ci]
//  [30720,39936): mp_w1 [32][32][9] -> Bm1 [(tap*32+co)*32+ci]
//  [39936,44544): mp_w2 [2][32][9] -> Bm2 [tap][16co][32ci] (co<2 real)
__global__ __launch_bounds__(256) void repack_all(const float* __restrict__ pe_w1,
                                                  const float* __restrict__ pe_w2,
                                                  const float* __restrict__ mp_w1,
                                                  const float* __restrict__ mp_w2,
                                                  unsigned short* __restrict__ B1,
                                                  unsigned short* __restrict__ B2,
                                                  unsigned short* __restrict__ Bm1,
                                                  unsigned short* __restrict__ Bm2) {
    int idx = blockIdx.x * 256 + threadIdx.x;
    if (idx < 5120) {
        int kh = idx / 1024, r = idx % 1024, o = r / 32, k = r % 32, dx = k >> 2, c = k & 3;
        float v = (dx < 5 && c < 3) ? pe_w1[o * 75 + c * 25 + kh * 5 + dx] : 0.f;
        B1[idx] = f2bf(v);
    } else if (idx < 30720) {
        int i = idx - 5120;
        int co = i / 800, r = i % 800, ci = r / 25, tap = r % 25;
        B2[(tap * 32 + co) * 32 + ci] = f2bf(pe_w2[i]);
    } else if (idx < 39936) {
        int i = idx - 30720;
        int co = i / 288, r = i % 288, ci = r / 9, tap = r % 9;
        Bm1[(tap * 32 + co) * 32 + ci] = f2bf(mp_w1[i]);
    } else if (idx < 44544) {
        int i = idx - 39936;
        int tap = i / 512, r = i % 512, co = r / 32, ci = r % 32;
        float v = (co < 2) ? mp_w2[co * 288 + ci * 9 + tap] : 0.f;
        Bm2[i] = f2bf(v);
    }
}

// Action MLP: actions[64,4] -> relu(256) -> 800; grid (4,64)
__global__ __launch_bounds__(256) void mlp_kernel(const float* __restrict__ actions,
                                                  const float* __restrict__ w1,
                                                  const float* __restrict__ b1,
                                                  const float* __restrict__ w2,
                                                  const float* __restrict__ b2,
                                                  float* __restrict__ aout) {
    int n = blockIdx.y;
    int t = threadIdx.x;
    __shared__ float hid[256];
    float a0 = actions[n * 4 + 0], a1 = actions[n * 4 + 1];
    float a2 = actions[n * 4 + 2], a3 = actions[n * 4 + 3];
    float acc = b1[t];
    acc += a0 * w1[0 * 256 + t] + a1 * w1[1 * 256 + t] +
           a2 * w1[2 * 256 + t] + a3 * w1[3 * 256 + t];
    hid[t] = fmaxf(acc, 0.0f);
    __syncthreads();
    int o = blockIdx.x * 200 + t;
    if (t < 200) {
        float s = b2[o];
        #pragma unroll 4
        for (int i = 0; i < 256; ++i) s += hid[i] * w2[i * 800 + o];
        aout[n * 800 + o] = s;
    }
}

// conv1 MFMA: imgp -> h1p. grid (64,64), block 256. Batched A-loads per kh.
__global__ __launch_bounds__(256, 4) void conv1_mfma(const unsigned short* __restrict__ imgp,
                                                     const short* __restrict__ B1,
                                                     const float* __restrict__ bias,
                                                     unsigned short* __restrict__ h1p) {
    const int tid = threadIdx.x;
    const int lane = tid & 63;
    const int w = tid >> 6;
    const int n = blockIdx.y;
    const int cohalf = w & 1;
    const int oy = blockIdx.x * 2 + (w >> 1);     // 0..127
    const int ml = lane & 15;
    const int kg = lane >> 4;

    bf16x8 bfrag[5];
    #pragma unroll
    for (int kh = 0; kh < 5; ++kh)
        bfrag[kh] = *(const bf16x8*)(B1 + ((kh * 32 + cohalf * 16 + ml) * 32 + kg * 8));
    const float bia = bias[cohalf * 16 + ml];
    const int co = cohalf * 16 + ml;

    f32x4 acc[8];
    #pragma unroll
    for (int t = 0; t < 8; ++t) acc[t] = (f32x4){bia, bia, bia, bia};

    for (int kh = 0; kh < 5; ++kh) {
        const unsigned short* rowbase = imgp + (size_t)(n * 260 + 2 * oy + kh) * 1056;
        bf16x8 af[8];
        #pragma unroll
        for (int t = 0; t < 8; ++t) {
            const int px0 = 2 * (16 * t + ml) + 2 * kg;
            af[t] = *(const bf16x8*)(rowbase + px0 * 4);
        }
        #pragma unroll
        for (int t = 0; t < 8; ++t)
            acc[t] = __builtin_amdgcn_mfma_f32_16x16x32_bf16(af[t], bfrag[kh], acc[t], 0, 0, 0);
    }
    #pragma unroll
    for (int t = 0; t < 8; ++t) {
        #pragma unroll
        for (int r = 0; r < 4; ++r) {
            const int px = 16 * t + kg * 4 + r;
            h1p[((size_t)(n * 132 + oy + 2) * 132 + px + 2) * 32 + co] = f2bf(fmaxf(acc[t][r], 0.f));
        }
    }
}

// conv2 via 32x32x16 MFMA, batched loads. B staged per-kh in LDS (rows padded
// to 40 shorts). grid (32,64), block 256.
__global__ __launch_bounds__(256, 4) void conv2_mfma32(const unsigned short* __restrict__ h1p,
                                                       const unsigned int* __restrict__ B,
                                                       const float* __restrict__ bias,
                                                       unsigned short* __restrict__ h2p) {
    __shared__ unsigned int Bs[5 * 32 * 20];       // 5 taps x 32 co x 40 bf16 = 12800 B
    const int tid = threadIdx.x;
    const int lane = tid & 63;
    const int w = tid >> 6;
    const int n = blockIdx.y;
    const int oy = blockIdx.x * 2 + (w >> 1);      // 0..63
    const int x0 = (w & 1) * 32;
    const int co = lane & 31;
    const int kgrp = lane >> 5;                    // 0/1

    const float bia = bias[co];
    f32x16 acc;
    #pragma unroll
    for (int r = 0; r < 16; ++r) acc[r] = bia;

    const unsigned short* bbase = (const unsigned short*)Bs + co * 40 + kgrp * 8;
    const int px0 = 2 * (x0 + co);                 // padded x base (stride 2)

    for (int kh = 0; kh < 5; ++kh) {
        if (kh) __syncthreads();
        const unsigned int* src = B + kh * 2560;
        #pragma unroll
        for (int i = tid; i < 2560; i += 256) {
            int row = i >> 4, p = i & 15;
            Bs[row * 20 + p] = src[i];
        }
        __syncthreads();

        const unsigned short* rowbase = h1p + (size_t)(n * 132 + 2 * oy + kh) * (132 * 32) + kgrp * 8;
        bf16x8 a[10], b[10];
        #pragma unroll
        for (int kw = 0; kw < 5; ++kw) {
            a[2 * kw]     = *(const bf16x8*)(rowbase + (px0 + kw) * 32);
            a[2 * kw + 1] = *(const bf16x8*)(rowbase + (px0 + kw) * 32 + 16);
            b[2 * kw]     = *(const bf16x8*)(bbase + kw * (32 * 40));
            b[2 * kw + 1] = *(const bf16x8*)(bbase + kw * (32 * 40) + 16);
        }
        #pragma unroll
        for (int kw = 0; kw < 5; ++kw) {
            acc = __builtin_amdgcn_mfma_f32_32x32x16_bf16(a[2 * kw], b[2 * kw], acc, 0, 0, 0);
            acc = __builtin_amdgcn_mfma_f32_32x32x16_bf16(a[2 * kw + 1], b[2 * kw + 1], acc, 0, 0, 0);
        }
    }
    #pragma unroll
    for (int r = 0; r < 16; ++r) {
        const int px = (r & 3) + 8 * (r >> 2) + 4 * kgrp;
        const int ox = x0 + px;
        h2p[((size_t)(n * 68 + oy + 2) * 68 + ox + 2) * 32 + co] = f2bf(fmaxf(acc[r], 0.f));
    }
}

// xconv: depthwise per-sample k5. Block = (n, 8-row strip); LDS = 12 rows x 68 x 32ci.
__global__ __launch_bounds__(256) void xconv_kernel(const unsigned short* __restrict__ h2p,
                                                    const float* __restrict__ ker,
                                                    unsigned short* __restrict__ sap) {
    __shared__ __align__(16) unsigned short tile[12 * 68 * 32];
    const int tid = threadIdx.x;
    const int n = blockIdx.x;
    const int rb = blockIdx.y;
    const unsigned short* src = h2p + (size_t)(n * 68 + rb * 8) * (68 * 32);
    for (int i = tid; i < 3264; i += 256)
        *(uint4*)(tile + i * 8) = *(const uint4*)(src + i * 8);
    const int ci = tid & 31, xg = tid >> 5;
    const float* kp = ker + (size_t)(n * 32 + ci) * 25;
    float k[25];
    #pragma unroll
    for (int t = 0; t < 25; ++t) k[t] = kp[t];
    __syncthreads();

    float acc[8][8];
    #pragma unroll
    for (int r = 0; r < 8; ++r)
        #pragma unroll
        for (int j = 0; j < 8; ++j) acc[r][j] = 0.f;

    #pragma unroll
    for (int ir = 0; ir < 12; ++ir) {
        float v[12];
        #pragma unroll
        for (int t = 0; t < 12; ++t)
            v[t] = bf2f(tile[(ir * 68 + xg * 8 + t) * 32 + ci]);
        #pragma unroll
        for (int kh = 0; kh < 5; ++kh) {
            const int r = ir - kh;
            if (r >= 0 && r < 8) {
                #pragma unroll
                for (int j = 0; j < 8; ++j) {
                    float s = acc[r][j];
                    #pragma unroll
                    for (int kw = 0; kw < 5; ++kw) s += k[kh * 5 + kw] * v[j + kw];
                    acc[r][j] = s;
                }
            }
        }
    }
    #pragma unroll
    for (int r = 0; r < 8; ++r)
        #pragma unroll
        for (int j = 0; j < 8; ++j)
            sap[((size_t)(n * 66 + rb * 8 + r + 1) * 66 + xg * 8 + j + 1) * 32 + ci] = f2bf(acc[r][j]);
}

// mp1 via 32x32x16 MFMA, batched loads. All 9 taps staged once in LDS. grid (32,64).
__global__ __launch_bounds__(256, 5) void mp1_mfma32(const unsigned short* __restrict__ sap,
                                                     const unsigned int* __restrict__ B,
                                                     const float* __restrict__ bias,
                                                     unsigned short* __restrict__ fp) {
    __shared__ unsigned int Bs[9 * 32 * 20];       // 23040 B
    const int tid = threadIdx.x;
    #pragma unroll
    for (int i = tid; i < 4608; i += 256) {
        int row = i >> 4, p = i & 15;
        Bs[row * 20 + p] = B[i];
    }
    __syncthreads();

    const int lane = tid & 63;
    const int w = tid >> 6;
    const int n = blockIdx.y;
    const int oy = blockIdx.x * 2 + (w >> 1);      // 0..63
    const int x0 = (w & 1) * 32;
    const int co = lane & 31;
    const int kgrp = lane >> 5;

    const float bia = bias[co];
    f32x16 acc;
    #pragma unroll
    for (int r = 0; r < 16; ++r) acc[r] = bia;

    const unsigned short* bbase = (const unsigned short*)Bs + co * 40 + kgrp * 8;
    const int px0 = x0 + co;                       // padded x base (stride 1)

    for (int kh = 0; kh < 3; ++kh) {
        const unsigned short* rowbase = sap + (size_t)(n * 66 + oy + kh) * (66 * 32) + kgrp * 8;
        bf16x8 a[6], b[6];
        #pragma unroll
        for (int kw = 0; kw < 3; ++kw) {
            const int tap = kh * 3 + kw;
            a[2 * kw]     = *(const bf16x8*)(rowbase + (px0 + kw) * 32);
            a[2 * kw + 1] = *(const bf16x8*)(rowbase + (px0 + kw) * 32 + 16);
            b[2 * kw]     = *(const bf16x8*)(bbase + tap * (32 * 40));
            b[2 * kw + 1] = *(const bf16x8*)(bbase + tap * (32 * 40) + 16);
        }
        #pragma unroll
        for (int kw = 0; kw < 3; ++kw) {
            acc = __builtin_amdgcn_mfma_f32_32x32x16_bf16(a[2 * kw], b[2 * kw], acc, 0, 0, 0);
            acc = __builtin_amdgcn_mfma_f32_32x32x16_bf16(a[2 * kw + 1], b[2 * kw + 1], acc, 0, 0, 0);
        }
    }
    #pragma unroll
    for (int r = 0; r < 16; ++r) {
        const int px = (r & 3) + 8 * (r >> 2) + 4 * kgrp;
        const int ox = x0 + px;
        fp[((size_t)(n * 66 + oy + 1) * 66 + ox + 1) * 32 + co] = f2bf(fmaxf(acc[r], 0.f));
    }
}

// mp2 MFMA: fp -> flow f32 NCHW. B 16 cols (co 0/1 real). Batched loads. grid (16,64).
__global__ __launch_bounds__(256, 4) void mp2_mfma(const unsigned short* __restrict__ fpb,
                                                   const short* __restrict__ B,
                                                   const float* __restrict__ bias,
                                                   float* __restrict__ out) {
    const int tid = threadIdx.x;
    const int lane = tid & 63;
    const int w = tid >> 6;
    const int n = blockIdx.y;
    const int oy = blockIdx.x * 4 + w;    // 0..63
    const int ml = lane & 15;
    const int kg = lane >> 4;

    bf16x8 bfrag[9];
    #pragma unroll
    for (int t = 0; t < 9; ++t)
        bfrag[t] = *(const bf16x8*)(B + ((t * 16 + ml) * 32 + kg * 8));
    const float bia = (ml < 2) ? bias[ml] : 0.f;

    f32x4 acc[4];
    #pragma unroll
    for (int t = 0; t < 4; ++t) acc[t] = (f32x4){bia, bia, bia, bia};

    for (int kh = 0; kh < 3; ++kh) {
        const unsigned short* rowbase = fpb + (size_t)(n * 66 + oy + kh) * (66 * 32);
        bf16x8 af[12];
        #pragma unroll
        for (int kw = 0; kw < 3; ++kw)
            #pragma unroll
            for (int t = 0; t < 4; ++t)
                af[kw * 4 + t] = *(const bf16x8*)(rowbase + (16 * t + ml + kw) * 32 + kg * 8);
        #pragma unroll
        for (int kw = 0; kw < 3; ++kw)
            #pragma unroll
            for (int t = 0; t < 4; ++t)
                acc[t] = __builtin_amdgcn_mfma_f32_16x16x32_bf16(af[kw * 4 + t], bfrag[kh * 3 + kw], acc[t], 0, 0, 0);
    }
    if (ml < 2) {
        #pragma unroll
        for (int t = 0; t < 4; ++t) {
            #pragma unroll
            for (int r = 0; r < 4; ++r) {
                const int px = 16 * t + kg * 4 + r;
                out[(size_t)n * 8192 + (size_t)ml * 4096 + (size_t)oy * 64 + px] = acc[t][r];
            }
        }
    }
}

extern "C" void kernel_launch(void* const* d_in, const int* in_sizes, int n_in,
                              void* d_out, int out_size, void* d_ws, size_t ws_size,
                              hipStream_t stream) {
    (void)in_sizes; (void)n_in; (void)out_size; (void)ws_size;
    const float* images  = (const float*)d_in[0];
    const float* actions = (const float*)d_in[1];
    const float* pe_w1   = (const float*)d_in[2];
    const float* pe_b1   = (const float*)d_in[3];
    const float* pe_w2   = (const float*)d_in[4];
    const float* pe_b2   = (const float*)d_in[5];
    const float* ae_w1   = (const float*)d_in[6];
    const float* ae_b1   = (const float*)d_in[7];
    const float* ae_w2   = (const float*)d_in[8];
    const float* ae_b2   = (const float*)d_in[9];
    const float* mp_w1   = (const float*)d_in[10];
    const float* mp_b1   = (const float*)d_in[11];
    const float* mp_w2   = (const float*)d_in[12];
    const float* mp_b2   = (const float*)d_in[13];
    float* out = (float*)d_out;

    char* ws = (char*)d_ws;
    float* a_ker          = (float*)(ws + 0);               // 204800
    unsigned short* B1    = (unsigned short*)(ws + 204800); // 10240
    unsigned short* B2    = (unsigned short*)(ws + 215040); // 51200
    unsigned short* Bm1   = (unsigned short*)(ws + 266240); // 18432
    unsigned short* Bm2   = (unsigned short*)(ws + 284672); // 9216
    unsigned short* h1p   = (unsigned short*)(ws + 524288);    // 71,368,704 -> 71,892,992
    unsigned short* imgp  = (unsigned short*)(ws + 71892992);  // 35,143,680 (dead after conv1)
    unsigned short* h2p   = (unsigned short*)(ws + 71892992);  // 18,939,904 (aliases imgp)
    unsigned short* sap   = (unsigned short*)(ws + 90832896);  // 17,842,176 (aliases imgp tail)
    unsigned short* fpb   = (unsigned short*)(ws + 108675072); // 17,842,176 -> 126,517,248

    repack_all<<<174, 256, 0, stream>>>(pe_w1, pe_w2, mp_w1, mp_w2, B1, B2, Bm1, Bm2);
    mlp_kernel<<<dim3(4, 64), 256, 0, stream>>>(actions, ae_w1, ae_b1, ae_w2, ae_b2, a_ker);
    zero_border2<<<dim3(64 * 132, 2), 64, 0, stream>>>((unsigned int*)h1p, 132, 2,
                                                       (unsigned int*)fpb, 66, 1);

    pad_img_kernel<<<64 * 260, 256, 0, stream>>>(images, imgp);
    conv1_mfma<<<dim3(64, 64), 256, 0, stream>>>(imgp, (const short*)B1, pe_b1, h1p);

    // imgp dead from here; its region is reused by h2p/sap
    zero_border2<<<dim3(64 * 68, 2), 64, 0, stream>>>((unsigned int*)h2p, 68, 2,
                                                      (unsigned int*)sap, 66, 1);

    conv2_mfma32<<<dim3(32, 64), 256, 0, stream>>>(h1p, (const unsigned int*)B2, pe_b2, h2p);
    xconv_kernel<<<dim3(64, 8), 256, 0, stream>>>(h2p, a_ker, sap);
    mp1_mfma32<<<dim3(32, 64), 256, 0, stream>>>(sap, (const unsigned int*)Bm1, mp_b1, fpb);
    mp2_mfma<<<dim3(16, 64), 256, 0, stream>>>(fpb, (const short*)Bm2, mp_b2, out);
}